// Round 1
// baseline (4234.963 us; speedup 1.0000x reference)
//
#include <hip/hip_runtime.h>
#include <stdint.h>
#include <stddef.h>

// ---------------- problem constants ----------------
#define NND 100000   // nodes
#define NED 200000   // edges
#define NG  128      // graphs
// D=32, D_LIN=128, F_EDGE=16, F_GRAPH=8, MP_TIMES=3, STEPS=3

typedef unsigned short us8 __attribute__((ext_vector_type(8)));

__device__ __forceinline__ float bf2f(unsigned short u){
  union{unsigned u; float f;} v; v.u = ((unsigned)u)<<16; return v.f;
}
__device__ __forceinline__ unsigned short f2bf(float f){
  union{float f; unsigned u;} v; v.f = f;
  unsigned r = v.u + 0x7FFFu + ((v.u>>16)&1u);
  return (unsigned short)(r>>16);
}
__device__ __forceinline__ float sigm(float x){ return 1.f/(1.f+__expf(-x)); }
__device__ __forceinline__ float tanh_(float x){ return 2.f/(1.f+__expf(-2.f*x)) - 1.f; }

// ---------------- fallback workspace (ws_size may be < 540MB) ----------------
static const size_t kNeed = 540000000ull;
static void* g_fb = nullptr;
namespace {
struct FB { FB(){ if (hipMalloc(&g_fb, kNeed) != hipSuccess) g_fb = nullptr; } };
static FB g_fb_init;
}

// ---------------- kernels ----------------

// nn2t[k][o*32+d] = nn2[k][d*32+o]; b2t[o*32+d] = b2[d*32+o]
__global__ __launch_bounds__(256) void k_prep(const float* __restrict__ nn2, const float* __restrict__ b2,
                                              float* __restrict__ nn2t, float* __restrict__ b2t){
  int tid = blockIdx.x*256 + threadIdx.x;     // 128*1024 total
  int k = tid >> 10, p = tid & 1023;
  int q = ((p & 31) << 5) + (p >> 5);
  nn2t[tid] = nn2[(k << 10) + q];
  if (k == 0) b2t[p] = b2[q];
}

// cur = relu(x @ lin0_w + lin0_b)
__global__ __launch_bounds__(256) void k_lin0(const float* __restrict__ x, const float* __restrict__ w,
                                              const float* __restrict__ b, float* __restrict__ cur){
  __shared__ float sw[1024]; __shared__ float sb[32];
  for (int i = threadIdx.x; i < 1024; i += 256) sw[i] = w[i];
  if (threadIdx.x < 32) sb[threadIdx.x] = b[threadIdx.x];
  __syncthreads();
  int n = blockIdx.x*256 + threadIdx.x;
  if (n >= NND) return;
  float xr[32], m[32];
  const float4* xp = (const float4*)(x + (size_t)n*32);
  #pragma unroll
  for (int i=0;i<8;i++){ float4 v = xp[i]; xr[4*i]=v.x; xr[4*i+1]=v.y; xr[4*i+2]=v.z; xr[4*i+3]=v.w; }
  #pragma unroll
  for (int o=0;o<32;o++){
    float acc = sb[o];
    #pragma unroll
    for (int d=0;d<32;d++) acc += xr[d]*sw[d*32+o];
    m[o] = fmaxf(acc, 0.f);
  }
  float4* op = (float4*)(cur + (size_t)n*32);
  #pragma unroll
  for (int i=0;i<8;i++){ float4 v; v.x=m[4*i]; v.y=m[4*i+1]; v.z=m[4*i+2]; v.w=m[4*i+3]; op[i]=v; }
}

// H = relu(edge_attr @ nn1 + b1)   [E,128]; 32 threads/edge, 4 outputs each
__global__ __launch_bounds__(256) void k_hidden(const float* __restrict__ ea, const float* __restrict__ w1,
                                                const float* __restrict__ b1, float* __restrict__ H){
  __shared__ float sw[2048]; __shared__ float sb[128];
  for (int i=threadIdx.x;i<2048;i+=256) sw[i]=w1[i];
  if (threadIdx.x<128) sb[threadIdx.x]=b1[threadIdx.x];
  __syncthreads();
  int gid = blockIdx.x*256 + threadIdx.x;     // E*32 total, exact
  int e = gid >> 5, q = gid & 31;
  float a[16];
  const float4* ap = (const float4*)(ea + (size_t)e*16);
  #pragma unroll
  for (int i=0;i<4;i++){ float4 v=ap[i]; a[4*i]=v.x; a[4*i+1]=v.y; a[4*i+2]=v.z; a[4*i+3]=v.w; }
  float c0=sb[q*4], c1=sb[q*4+1], c2=sb[q*4+2], c3=sb[q*4+3];
  #pragma unroll
  for (int k=0;k<16;k++){
    float av=a[k]; const float* wr = &sw[k*128 + q*4];
    c0 += av*wr[0]; c1 += av*wr[1]; c2 += av*wr[2]; c3 += av*wr[3];
  }
  float4 o; o.x=fmaxf(c0,0.f); o.y=fmaxf(c1,0.f); o.z=fmaxf(c2,0.f); o.w=fmaxf(c3,0.f);
  *(float4*)(H + (size_t)e*128 + q*4) = o;
}

// ew[e][p] = H[e,:] @ nn2t[:,p] + b2t[p], bf16 out.  Tile 64 edges x 128 cols, 256 thr, 4x8 micro.
__global__ __launch_bounds__(256) void k_gemm2(const float* __restrict__ H, const float* __restrict__ Bt,
                                               const float* __restrict__ b2t, unsigned short* __restrict__ ew){
  __shared__ float As[16][64];
  __shared__ float Bs[16][128];
  int e0 = blockIdx.x*64, c0 = blockIdx.y*128;
  int tid = threadIdx.x;
  int tx = tid & 15, ty = tid >> 4;           // cols tx*8..+7, rows ty*4..+3
  float bias[8];
  #pragma unroll
  for (int j=0;j<8;j++) bias[j] = b2t[c0 + tx*8 + j];
  float acc[4][8] = {};
  for (int kk=0; kk<128; kk+=16){
    {
      int r = tid >> 2, kq = tid & 3;
      float4 v = *(const float4*)(H + (size_t)(e0+r)*128 + kk + kq*4);
      As[kq*4+0][r]=v.x; As[kq*4+1][r]=v.y; As[kq*4+2][r]=v.z; As[kq*4+3][r]=v.w;
    }
    #pragma unroll
    for (int t=0;t<2;t++){
      int v4 = tid + t*256;
      int k = v4 >> 5, c = (v4 & 31)*4;
      *(float4*)&Bs[k][c] = *(const float4*)(Bt + (size_t)(kk+k)*1024 + c0 + c);
    }
    __syncthreads();
    #pragma unroll
    for (int k=0;k<16;k++){
      float a[4], b[8];
      #pragma unroll
      for (int i=0;i<4;i++) a[i]=As[k][ty*4+i];
      #pragma unroll
      for (int j=0;j<8;j++) b[j]=Bs[k][tx*8+j];
      #pragma unroll
      for (int i=0;i<4;i++)
        #pragma unroll
        for (int j=0;j<8;j++) acc[i][j] += a[i]*b[j];
    }
    __syncthreads();
  }
  #pragma unroll
  for (int i=0;i<4;i++){
    int e = e0 + ty*4 + i;
    us8 pk;
    #pragma unroll
    for (int j=0;j<8;j++) pk[j] = f2bf(acc[i][j] + bias[j]);
    *(us8*)(ew + (size_t)e*1024 + c0 + tx*8) = pk;
  }
}

__global__ __launch_bounds__(256) void k_counts(const int* __restrict__ batch, int* __restrict__ counts){
  int i = blockIdx.x*256 + threadIdx.x;
  if (i < NND) atomicAdd(&counts[batch[i]], 1);
}
__global__ void k_scan(const int* __restrict__ counts, int* __restrict__ starts){
  if (threadIdx.x == 0){ int s = 0; for (int g=0; g<NG; g++){ starts[g]=s; s+=counts[g]; } }
}
__global__ __launch_bounds__(256) void k_deg(const int* __restrict__ dst, float* __restrict__ deg){
  int e = blockIdx.x*256 + threadIdx.x;
  if (e < NED) atomicAdd(&deg[dst[e]], 1.f);
}

// msg[e,o] = sum_d cur[src[e],d]*ew[e][o*32+d];  atomicAdd into agg[dst,o].  32 lanes/edge.
__global__ __launch_bounds__(256) void k_msg(const float* __restrict__ cur, const unsigned short* __restrict__ ew,
                                             const int* __restrict__ src, const int* __restrict__ dst,
                                             float* __restrict__ agg){
  __shared__ float s_lds[8][32];
  int gid = blockIdx.x*256 + threadIdx.x;     // E*32 exact
  int e = gid >> 5, o = gid & 31, le = threadIdx.x >> 5;
  int s = src[e], t = dst[e];
  s_lds[le][o] = cur[(size_t)s*32 + o];
  __syncthreads();
  float acc = 0.f;
  const unsigned short* er = ew + (size_t)e*1024 + o*32;
  const float* sr = s_lds[le];
  #pragma unroll
  for (int d0=0; d0<32; d0+=8){
    us8 u = *(const us8*)(er + d0);
    #pragma unroll
    for (int j=0;j<8;j++) acc += bf2f(u[j]) * sr[d0+j];
  }
  atomicAdd(&agg[(size_t)t*32 + o], acc);
}

// m = relu(cur@root + agg/deg + cb); GRU(h=cur, in=m) -> cur (in place, per-node)
__global__ __launch_bounds__(256) void k_gru(float* __restrict__ cur, const float* __restrict__ agg,
                                             const float* __restrict__ deg,
                                             const float* __restrict__ root_w, const float* __restrict__ conv_b,
                                             const float* __restrict__ wih, const float* __restrict__ whh,
                                             const float* __restrict__ bih, const float* __restrict__ bhh){
  __shared__ float s_root[1024], s_wih[3072], s_whh[3072], s_cb[32], s_bih[96], s_bhh[96];
  for (int i=threadIdx.x;i<1024;i+=256) s_root[i]=root_w[i];
  for (int i=threadIdx.x;i<3072;i+=256){ s_wih[i]=wih[i]; s_whh[i]=whh[i]; }
  if (threadIdx.x<32) s_cb[threadIdx.x]=conv_b[threadIdx.x];
  if (threadIdx.x<96){ s_bih[threadIdx.x]=bih[threadIdx.x]; s_bhh[threadIdx.x]=bhh[threadIdx.x]; }
  __syncthreads();
  int n = blockIdx.x*256 + threadIdx.x;
  if (n >= NND) return;
  float c[32], a[32], m[32];
  const float4* cp = (const float4*)(cur + (size_t)n*32);
  const float4* apg = (const float4*)(agg + (size_t)n*32);
  #pragma unroll
  for (int i=0;i<8;i++){ float4 v=cp[i]; c[4*i]=v.x; c[4*i+1]=v.y; c[4*i+2]=v.z; c[4*i+3]=v.w; }
  #pragma unroll
  for (int i=0;i<8;i++){ float4 v=apg[i]; a[4*i]=v.x; a[4*i+1]=v.y; a[4*i+2]=v.z; a[4*i+3]=v.w; }
  float idg = 1.f / fmaxf(deg[n], 1.f);
  #pragma unroll
  for (int o=0;o<32;o++){
    float acc = s_cb[o] + a[o]*idg;
    #pragma unroll
    for (int d=0;d<32;d++) acc += c[d]*s_root[d*32+o];
    m[o] = fmaxf(acc, 0.f);
  }
  float hn[32];
  #pragma unroll
  for (int j=0;j<32;j++){
    float gr=s_bih[j], gz=s_bih[32+j], gn=s_bih[64+j];
    float hr=s_bhh[j], hz=s_bhh[32+j], hh=s_bhh[64+j];
    #pragma unroll
    for (int k=0;k<32;k++){
      float mk=m[k], ck=c[k];
      gr += mk*s_wih[k*96+j];    gz += mk*s_wih[k*96+32+j]; gn += mk*s_wih[k*96+64+j];
      hr += ck*s_whh[k*96+j];    hz += ck*s_whh[k*96+32+j]; hh += ck*s_whh[k*96+64+j];
    }
    float r = sigm(gr+hr);
    float z = sigm(gz+hz);
    float nn = tanh_(gn + r*hh);
    hn[j] = (1.f-z)*nn + z*c[j];
  }
  float4* op = (float4*)(cur + (size_t)n*32);
  #pragma unroll
  for (int i=0;i<8;i++){ float4 v; v.x=hn[4*i]; v.y=hn[4*i+1]; v.z=hn[4*i+2]; v.w=hn[4*i+3]; op[i]=v; }
}

// LSTM over 128 graphs (single block). hs/cs updated in place; reads prev hs + rvec (= q_star).
__global__ __launch_bounds__(128) void k_lstm(float* __restrict__ hs, float* __restrict__ cs,
                                              const float* __restrict__ rvec,
                                              const float* __restrict__ wih, const float* __restrict__ whh,
                                              const float* __restrict__ bih, const float* __restrict__ bhh){
  __shared__ float swih[8192];   // 64x128
  __shared__ float swhh[4096];   // 32x128
  __shared__ float sb[128];
  int tid = threadIdx.x;
  for (int i=tid;i<8192;i+=128) swih[i]=wih[i];
  for (int i=tid;i<4096;i+=128) swhh[i]=whh[i];
  sb[tid] = bih[tid] + bhh[tid];
  __syncthreads();
  int g = tid;
  float hp[32], rp[32], cp[32];
  #pragma unroll
  for (int k=0;k<32;k++){ hp[k]=hs[g*32+k]; rp[k]=rvec[g*32+k]; cp[k]=cs[g*32+k]; }
  for (int j=0;j<32;j++){
    float gI=sb[j], gF=sb[32+j], gG=sb[64+j], gO=sb[96+j];
    #pragma unroll
    for (int k=0;k<32;k++){
      float h=hp[k], r=rp[k];
      gI += h*(swih[k*128+j]    + swhh[k*128+j])    + r*swih[(32+k)*128+j];
      gF += h*(swih[k*128+32+j] + swhh[k*128+32+j]) + r*swih[(32+k)*128+32+j];
      gG += h*(swih[k*128+64+j] + swhh[k*128+64+j]) + r*swih[(32+k)*128+64+j];
      gO += h*(swih[k*128+96+j] + swhh[k*128+96+j]) + r*swih[(32+k)*128+96+j];
    }
    float cn = sigm(gF)*cp[j] + sigm(gI)*tanh_(gG);
    cs[g*32+j] = cn;
    hs[g*32+j] = sigm(gO)*tanh_(cn);
  }
}

// Per-graph segment softmax attention + weighted sum (batch sorted -> contiguous segments)
__global__ __launch_bounds__(256) void k_attn(const float* __restrict__ cur, const float* __restrict__ hs,
                                              const int* __restrict__ starts, const int* __restrict__ counts,
                                              float* __restrict__ evals, float* __restrict__ rvec){
  int g = blockIdx.x;
  int s0 = starts[g], cnt = counts[g];
  int tid = threadIdx.x;
  __shared__ float red[256];
  __shared__ float sh[32];
  __shared__ float srv[32];
  if (tid < 32){ sh[tid] = hs[g*32+tid]; srv[tid] = 0.f; }
  __syncthreads();
  float lmax = -3.4e38f;
  for (int i = tid; i < cnt; i += 256){
    const float4* cp = (const float4*)(cur + (size_t)(s0+i)*32);
    float acc = 0.f;
    #pragma unroll
    for (int q=0;q<8;q++){ float4 v = cp[q]; acc += v.x*sh[q*4]+v.y*sh[q*4+1]+v.z*sh[q*4+2]+v.w*sh[q*4+3]; }
    evals[s0+i] = acc;
    lmax = fmaxf(lmax, acc);
  }
  red[tid] = lmax; __syncthreads();
  #pragma unroll
  for (int st=128; st>0; st>>=1){ if (tid<st) red[tid]=fmaxf(red[tid],red[tid+st]); __syncthreads(); }
  float mx = red[0]; __syncthreads();
  float lsum = 0.f;
  for (int i = tid; i < cnt; i += 256){
    float w = __expf(evals[s0+i]-mx);
    evals[s0+i] = w;
    lsum += w;
  }
  red[tid] = lsum; __syncthreads();
  #pragma unroll
  for (int st=128; st>0; st>>=1){ if (tid<st) red[tid]+=red[tid+st]; __syncthreads(); }
  float inv = 1.f/red[0]; __syncthreads();
  float rv[32];
  #pragma unroll
  for (int k=0;k<32;k++) rv[k]=0.f;
  for (int i = tid; i < cnt; i += 256){
    float a = evals[s0+i]*inv;
    const float4* cp = (const float4*)(cur + (size_t)(s0+i)*32);
    #pragma unroll
    for (int q=0;q<8;q++){ float4 v=cp[q]; rv[q*4]+=a*v.x; rv[q*4+1]+=a*v.y; rv[q*4+2]+=a*v.z; rv[q*4+3]+=a*v.w; }
  }
  #pragma unroll
  for (int k=0;k<32;k++){
    float v = rv[k];
    #pragma unroll
    for (int o=32;o>0;o>>=1) v += __shfl_down(v, o, 64);
    if ((tid&63)==0) atomicAdd(&srv[k], v);
  }
  __syncthreads();
  if (tid < 32) rvec[g*32+tid] = srv[tid];
}

// out[g] = relu([hs, rvec, ga] @ lin1 + b1) @ lin2 + b2
__global__ __launch_bounds__(128) void k_final(const float* __restrict__ hs, const float* __restrict__ rvec,
                                               const float* __restrict__ ga,
                                               const float* __restrict__ w1, const float* __restrict__ b1,
                                               const float* __restrict__ w2, const float* __restrict__ b2,
                                               float* __restrict__ out){
  __shared__ float sw1[2304]; __shared__ float sb1[32]; __shared__ float sw2[32];
  int tid = threadIdx.x;
  for (int i=tid;i<2304;i+=128) sw1[i]=w1[i];
  if (tid<32){ sb1[tid]=b1[tid]; sw2[tid]=w2[tid]; }
  __syncthreads();
  int g = tid;
  float hp[32], rp[32], gp[8];
  #pragma unroll
  for (int k=0;k<32;k++){ hp[k]=hs[g*32+k]; rp[k]=rvec[g*32+k]; }
  #pragma unroll
  for (int k=0;k<8;k++) gp[k]=ga[g*8+k];
  float o = b2[0];
  for (int j=0;j<32;j++){
    float acc = sb1[j];
    #pragma unroll
    for (int k=0;k<32;k++) acc += hp[k]*sw1[k*32+j];
    #pragma unroll
    for (int k=0;k<32;k++) acc += rp[k]*sw1[(32+k)*32+j];
    #pragma unroll
    for (int k=0;k<8;k++)  acc += gp[k]*sw1[(64+k)*32+j];
    o += fmaxf(acc,0.f)*sw2[j];
  }
  out[g] = o;
}

// ---------------- launch ----------------
extern "C" void kernel_launch(void* const* d_in, const int* in_sizes, int n_in,
                              void* d_out, int out_size, void* d_ws, size_t ws_size,
                              hipStream_t stream){
  (void)in_sizes; (void)n_in; (void)out_size;
  const float* x         = (const float*)d_in[0];
  const float* edge_attr = (const float*)d_in[1];
  const float* graph_attr= (const float*)d_in[2];
  const int*   eidx      = (const int*)d_in[3];
  const int*   batch     = (const int*)d_in[4];
  const float* lin0_w    = (const float*)d_in[5];
  const float* lin0_b    = (const float*)d_in[6];
  const float* nn1_w     = (const float*)d_in[7];
  const float* nn1_b     = (const float*)d_in[8];
  const float* nn2_w     = (const float*)d_in[9];
  const float* nn2_b     = (const float*)d_in[10];
  const float* root_w    = (const float*)d_in[11];
  const float* conv_b    = (const float*)d_in[12];
  const float* gru_wih   = (const float*)d_in[13];
  const float* gru_whh   = (const float*)d_in[14];
  const float* gru_bih   = (const float*)d_in[15];
  const float* gru_bhh   = (const float*)d_in[16];
  const float* lstm_wih  = (const float*)d_in[17];
  const float* lstm_whh  = (const float*)d_in[18];
  const float* lstm_bih  = (const float*)d_in[19];
  const float* lstm_bhh  = (const float*)d_in[20];
  const float* lin1_w    = (const float*)d_in[21];
  const float* lin1_b    = (const float*)d_in[22];
  const float* lin2_w    = (const float*)d_in[23];
  const float* lin2_b    = (const float*)d_in[24];
  const int* src = eidx;
  const int* dst = eidx + NED;

  char* pool = (ws_size >= kNeed) ? (char*)d_ws : (char*)g_fb;
  if (!pool) pool = (char*)d_ws;   // last resort
  size_t off = 0;
  auto alloc = [&](size_t bytes)->char* {
    char* p = pool + off; off += (bytes + 511) & ~(size_t)511; return p;
  };
  unsigned short* ew  = (unsigned short*)alloc((size_t)NED*1024*2);  // 409.6 MB, bf16 [e][o*32+d]
  float* H    = (float*)alloc((size_t)NED*128*4);                    // 102.4 MB
  float* cur  = (float*)alloc((size_t)NND*32*4);
  float* agg  = (float*)alloc((size_t)NND*32*4);
  float* deg  = (float*)alloc((size_t)NND*4);
  float* ev   = (float*)alloc((size_t)NND*4);
  float* nn2t = (float*)alloc(128*1024*4);
  float* b2t  = (float*)alloc(1024*4);
  float* hsb  = (float*)alloc(NG*32*4);
  float* csb  = (float*)alloc(NG*32*4);
  float* rvb  = (float*)alloc(NG*32*4);
  int*   counts = (int*)alloc(512);
  int*   startsb= (int*)alloc(512);

  hipMemsetAsync(counts, 0, 512, stream);
  hipMemsetAsync(deg, 0, (size_t)NND*4, stream);
  hipMemsetAsync(hsb, 0, NG*32*4, stream);
  hipMemsetAsync(csb, 0, NG*32*4, stream);
  hipMemsetAsync(rvb, 0, NG*32*4, stream);

  k_prep<<<512, 256, 0, stream>>>(nn2_w, nn2_b, nn2t, b2t);
  k_lin0<<<(NND+255)/256, 256, 0, stream>>>(x, lin0_w, lin0_b, cur);
  k_counts<<<(NND+255)/256, 256, 0, stream>>>(batch, counts);
  k_scan<<<1, 64, 0, stream>>>(counts, startsb);
  k_deg<<<(NED+255)/256, 256, 0, stream>>>(dst, deg);
  k_hidden<<<NED*32/256, 256, 0, stream>>>(edge_attr, nn1_w, nn1_b, H);
  k_gemm2<<<dim3(NED/64, 8), 256, 0, stream>>>(H, nn2t, b2t, ew);

  for (int it=0; it<3; ++it){
    hipMemsetAsync(agg, 0, (size_t)NND*32*4, stream);
    k_msg<<<NED*32/256, 256, 0, stream>>>(cur, ew, src, dst, agg);
    k_gru<<<(NND+255)/256, 256, 0, stream>>>(cur, agg, deg, root_w, conv_b,
                                             gru_wih, gru_whh, gru_bih, gru_bhh);
  }
  for (int st=0; st<3; ++st){
    k_lstm<<<1, 128, 0, stream>>>(hsb, csb, rvb, lstm_wih, lstm_whh, lstm_bih, lstm_bhh);
    k_attn<<<NG, 256, 0, stream>>>(cur, hsb, startsb, counts, ev, rvb);
  }
  k_final<<<1, 128, 0, stream>>>(hsb, rvb, graph_attr, lin1_w, lin1_b, lin2_w, lin2_b, (float*)d_out);
}

// Round 2
// 1992.054 us; speedup vs baseline: 2.1259x; 2.1259x over previous
//
#include <hip/hip_runtime.h>
#include <stdint.h>
#include <stddef.h>

// ---------------- problem constants ----------------
#define NND 100000   // nodes
#define NED 200000   // edges
#define NG  128      // graphs
// D=32, D_LIN=128, F_EDGE=16, F_GRAPH=8, MP_TIMES=3, STEPS=3

typedef unsigned short us8 __attribute__((ext_vector_type(8)));

__device__ __forceinline__ float bf2f(unsigned short u){
  union{unsigned u; float f;} v; v.u = ((unsigned)u)<<16; return v.f;
}
__device__ __forceinline__ unsigned short f2bf(float f){
  union{float f; unsigned u;} v; v.f = f;
  unsigned r = v.u + 0x7FFFu + ((v.u>>16)&1u);
  return (unsigned short)(r>>16);
}
__device__ __forceinline__ float sigm(float x){ return 1.f/(1.f+__expf(-x)); }
__device__ __forceinline__ float tanh_(float x){ return 2.f/(1.f+__expf(-2.f*x)) - 1.f; }

// ---------------- fallback workspace (ws_size may be < 540MB) ----------------
static const size_t kNeed = 540000000ull;
static void* g_fb = nullptr;
namespace {
struct FB { FB(){ if (hipMalloc(&g_fb, kNeed) != hipSuccess) g_fb = nullptr; } };
static FB g_fb_init;
}

// ---------------- kernels ----------------

// nn2t[k][o*32+d] = nn2[k][d*32+o]; b2t[o*32+d] = b2[d*32+o]
__global__ __launch_bounds__(256) void k_prep(const float* __restrict__ nn2, const float* __restrict__ b2,
                                              float* __restrict__ nn2t, float* __restrict__ b2t){
  int tid = blockIdx.x*256 + threadIdx.x;     // 128*1024 total
  int k = tid >> 10, p = tid & 1023;
  int q = ((p & 31) << 5) + (p >> 5);
  nn2t[tid] = nn2[(k << 10) + q];
  if (k == 0) b2t[p] = b2[q];
}

// cur = relu(x @ lin0_w + lin0_b)  -- 32 lanes per node, lane j owns output j
__global__ __launch_bounds__(256) void k_lin0(const float* __restrict__ x, const float* __restrict__ w,
                                              const float* __restrict__ b, float* __restrict__ cur){
  __shared__ float sw[1024]; __shared__ float sb[32];
  __shared__ float sx[8][32];
  for (int i = threadIdx.x; i < 1024; i += 256) sw[i] = w[i];
  if (threadIdx.x < 32) sb[threadIdx.x] = b[threadIdx.x];
  __syncthreads();
  int ln = threadIdx.x >> 5, j = threadIdx.x & 31;
  for (int it = 0; it < 4; ++it){
    int n = (blockIdx.x*4 + it)*8 + ln;
    if (n >= NND) return;
    float xj = x[(size_t)n*32 + j];
    sx[ln][j] = xj;                       // wave-synchronous within the 32-lane group
    float acc = sb[j];
    #pragma unroll
    for (int d=0; d<32; d++) acc += sx[ln][d]*sw[d*32+j];
    cur[(size_t)n*32 + j] = fmaxf(acc, 0.f);
  }
}

// H = relu(edge_attr @ nn1 + b1)   [E,128]; 32 threads/edge, 4 outputs each
__global__ __launch_bounds__(256) void k_hidden(const float* __restrict__ ea, const float* __restrict__ w1,
                                                const float* __restrict__ b1, float* __restrict__ H){
  __shared__ float sw[2048]; __shared__ float sb[128];
  for (int i=threadIdx.x;i<2048;i+=256) sw[i]=w1[i];
  if (threadIdx.x<128) sb[threadIdx.x]=b1[threadIdx.x];
  __syncthreads();
  int gid = blockIdx.x*256 + threadIdx.x;     // E*32 total, exact
  int e = gid >> 5, q = gid & 31;
  float a[16];
  const float4* ap = (const float4*)(ea + (size_t)e*16);
  #pragma unroll
  for (int i=0;i<4;i++){ float4 v=ap[i]; a[4*i]=v.x; a[4*i+1]=v.y; a[4*i+2]=v.z; a[4*i+3]=v.w; }
  float c0=sb[q*4], c1=sb[q*4+1], c2=sb[q*4+2], c3=sb[q*4+3];
  #pragma unroll
  for (int k=0;k<16;k++){
    float av=a[k]; const float* wr = &sw[k*128 + q*4];
    c0 += av*wr[0]; c1 += av*wr[1]; c2 += av*wr[2]; c3 += av*wr[3];
  }
  float4 o; o.x=fmaxf(c0,0.f); o.y=fmaxf(c1,0.f); o.z=fmaxf(c2,0.f); o.w=fmaxf(c3,0.f);
  *(float4*)(H + (size_t)e*128 + q*4) = o;
}

// ew[e][p] = H[e,:] @ nn2t[:,p] + b2t[p], bf16 out.  Tile 64 edges x 128 cols, 256 thr, 4x8 micro.
__global__ __launch_bounds__(256) void k_gemm2(const float* __restrict__ H, const float* __restrict__ Bt,
                                               const float* __restrict__ b2t, unsigned short* __restrict__ ew){
  __shared__ float As[16][64];
  __shared__ float Bs[16][128];
  int e0 = blockIdx.x*64, c0 = blockIdx.y*128;
  int tid = threadIdx.x;
  int tx = tid & 15, ty = tid >> 4;           // cols tx*8..+7, rows ty*4..+3
  float bias[8];
  #pragma unroll
  for (int j=0;j<8;j++) bias[j] = b2t[c0 + tx*8 + j];
  float acc[4][8] = {};
  for (int kk=0; kk<128; kk+=16){
    {
      int r = tid >> 2, kq = tid & 3;
      float4 v = *(const float4*)(H + (size_t)(e0+r)*128 + kk + kq*4);
      As[kq*4+0][r]=v.x; As[kq*4+1][r]=v.y; As[kq*4+2][r]=v.z; As[kq*4+3][r]=v.w;
    }
    #pragma unroll
    for (int t=0;t<2;t++){
      int v4 = tid + t*256;
      int k = v4 >> 5, c = (v4 & 31)*4;
      *(float4*)&Bs[k][c] = *(const float4*)(Bt + (size_t)(kk+k)*1024 + c0 + c);
    }
    __syncthreads();
    #pragma unroll
    for (int k=0;k<16;k++){
      float a[4], b[8];
      #pragma unroll
      for (int i=0;i<4;i++) a[i]=As[k][ty*4+i];
      #pragma unroll
      for (int j=0;j<8;j++) b[j]=Bs[k][tx*8+j];
      #pragma unroll
      for (int i=0;i<4;i++)
        #pragma unroll
        for (int j=0;j<8;j++) acc[i][j] += a[i]*b[j];
    }
    __syncthreads();
  }
  #pragma unroll
  for (int i=0;i<4;i++){
    int e = e0 + ty*4 + i;
    us8 pk;
    #pragma unroll
    for (int j=0;j<8;j++) pk[j] = f2bf(acc[i][j] + bias[j]);
    *(us8*)(ew + (size_t)e*1024 + c0 + tx*8) = pk;
  }
}

__global__ __launch_bounds__(256) void k_counts(const int* __restrict__ batch, int* __restrict__ counts){
  int i = blockIdx.x*256 + threadIdx.x;
  if (i < NND) atomicAdd(&counts[batch[i]], 1);
}
__global__ void k_scan(const int* __restrict__ counts, int* __restrict__ starts){
  if (threadIdx.x == 0){ int s = 0; for (int g=0; g<NG; g++){ starts[g]=s; s+=counts[g]; } }
}
__global__ __launch_bounds__(256) void k_deg(const int* __restrict__ dst, float* __restrict__ deg){
  int e = blockIdx.x*256 + threadIdx.x;
  if (e < NED) atomicAdd(&deg[dst[e]], 1.f);
}

// msg[e,o] = sum_d cur[src[e],d]*ew[e][o*32+d];  atomicAdd into agg[dst,o].  32 lanes/edge.
__global__ __launch_bounds__(256) void k_msg(const float* __restrict__ cur, const unsigned short* __restrict__ ew,
                                             const int* __restrict__ src, const int* __restrict__ dst,
                                             float* __restrict__ agg){
  __shared__ float s_lds[8][32];
  int gid = blockIdx.x*256 + threadIdx.x;     // E*32 exact
  int e = gid >> 5, o = gid & 31, le = threadIdx.x >> 5;
  int s = src[e], t = dst[e];
  s_lds[le][o] = cur[(size_t)s*32 + o];
  __syncthreads();
  float acc = 0.f;
  const unsigned short* er = ew + (size_t)e*1024 + o*32;
  const float* sr = s_lds[le];
  #pragma unroll
  for (int d0=0; d0<32; d0+=8){
    us8 u = *(const us8*)(er + d0);
    #pragma unroll
    for (int j=0;j<8;j++) acc += bf2f(u[j]) * sr[d0+j];
  }
  atomicAdd(&agg[(size_t)t*32 + o], acc);
}

// m = relu(cur@root + agg/deg + cb); GRU(h=cur, in=m) -> cur.
// 32 lanes per node (lane j owns channel j); 8 nodes per 256-thr block-slice, 4 slices.
__global__ __launch_bounds__(256) void k_gru(float* __restrict__ cur, const float* __restrict__ agg,
                                             const float* __restrict__ deg,
                                             const float* __restrict__ root_w, const float* __restrict__ conv_b,
                                             const float* __restrict__ wih, const float* __restrict__ whh,
                                             const float* __restrict__ bih, const float* __restrict__ bhh){
  __shared__ float s_root[1024], s_wih[3072], s_whh[3072], s_cb[32], s_bih[96], s_bhh[96];
  __shared__ float s_c[8][32], s_m[8][32];
  for (int i=threadIdx.x;i<1024;i+=256) s_root[i]=root_w[i];
  for (int i=threadIdx.x;i<3072;i+=256){ s_wih[i]=wih[i]; s_whh[i]=whh[i]; }
  if (threadIdx.x<32) s_cb[threadIdx.x]=conv_b[threadIdx.x];
  if (threadIdx.x<96){ s_bih[threadIdx.x]=bih[threadIdx.x]; s_bhh[threadIdx.x]=bhh[threadIdx.x]; }
  __syncthreads();
  int ln = threadIdx.x >> 5, j = threadIdx.x & 31;
  // 3125 blocks * 4 iters * 8 nodes = 100000 exactly
  for (int it = 0; it < 4; ++it){
    int n = (blockIdx.x*4 + it)*8 + ln;
    float c_j = cur[(size_t)n*32 + j];
    float a_j = agg[(size_t)n*32 + j];
    s_c[ln][j] = c_j;                  // within-wave visibility (group is half a wave64)
    float idg = 1.f / fmaxf(deg[n], 1.f);
    float acc = s_cb[j] + a_j*idg;
    #pragma unroll
    for (int d=0; d<32; d++) acc += s_c[ln][d]*s_root[d*32+j];
    float m_j = fmaxf(acc, 0.f);
    s_m[ln][j] = m_j;
    float gr = s_bih[j], gz = s_bih[32+j], gn = s_bih[64+j];
    float hr = s_bhh[j], hz = s_bhh[32+j], hh = s_bhh[64+j];
    #pragma unroll
    for (int k=0;k<32;k++){
      float mk = s_m[ln][k], ck = s_c[ln][k];
      gr += mk*s_wih[k*96+j];
      gz += mk*s_wih[k*96+32+j];
      gn += mk*s_wih[k*96+64+j];
      hr += ck*s_whh[k*96+j];
      hz += ck*s_whh[k*96+32+j];
      hh += ck*s_whh[k*96+64+j];
    }
    float r = sigm(gr+hr);
    float z = sigm(gz+hz);
    float nnv = tanh_(gn + r*hh);
    cur[(size_t)n*32 + j] = (1.f-z)*nnv + z*c_j;
  }
}

// LSTM over 128 graphs (single block). hs/cs updated in place; reads prev hs + rvec (= q_star).
__global__ __launch_bounds__(128) void k_lstm(float* __restrict__ hs, float* __restrict__ cs,
                                              const float* __restrict__ rvec,
                                              const float* __restrict__ wih, const float* __restrict__ whh,
                                              const float* __restrict__ bih, const float* __restrict__ bhh){
  __shared__ float swih[8192];   // 64x128
  __shared__ float swhh[4096];   // 32x128
  __shared__ float sb[128];
  int tid = threadIdx.x;
  for (int i=tid;i<8192;i+=128) swih[i]=wih[i];
  for (int i=tid;i<4096;i+=128) swhh[i]=whh[i];
  sb[tid] = bih[tid] + bhh[tid];
  __syncthreads();
  int g = tid;
  float hp[32], rp[32], cp[32];
  #pragma unroll
  for (int k=0;k<32;k++){ hp[k]=hs[g*32+k]; rp[k]=rvec[g*32+k]; cp[k]=cs[g*32+k]; }
  for (int j=0;j<32;j++){
    float gI=sb[j], gF=sb[32+j], gG=sb[64+j], gO=sb[96+j];
    #pragma unroll
    for (int k=0;k<32;k++){
      float h=hp[k], r=rp[k];
      gI += h*(swih[k*128+j]    + swhh[k*128+j])    + r*swih[(32+k)*128+j];
      gF += h*(swih[k*128+32+j] + swhh[k*128+32+j]) + r*swih[(32+k)*128+32+j];
      gG += h*(swih[k*128+64+j] + swhh[k*128+64+j]) + r*swih[(32+k)*128+64+j];
      gO += h*(swih[k*128+96+j] + swhh[k*128+96+j]) + r*swih[(32+k)*128+96+j];
    }
    float cn = sigm(gF)*cp[j] + sigm(gI)*tanh_(gG);
    cs[g*32+j] = cn;
    hs[g*32+j] = sigm(gO)*tanh_(cn);
  }
}

// Per-graph segment softmax attention + weighted sum (batch sorted -> contiguous segments)
__global__ __launch_bounds__(256) void k_attn(const float* __restrict__ cur, const float* __restrict__ hs,
                                              const int* __restrict__ starts, const int* __restrict__ counts,
                                              float* __restrict__ evals, float* __restrict__ rvec){
  int g = blockIdx.x;
  int s0 = starts[g], cnt = counts[g];
  int tid = threadIdx.x;
  __shared__ float red[256];
  __shared__ float sh[32];
  __shared__ float srv[32];
  if (tid < 32){ sh[tid] = hs[g*32+tid]; srv[tid] = 0.f; }
  __syncthreads();
  float lmax = -3.4e38f;
  for (int i = tid; i < cnt; i += 256){
    const float4* cp = (const float4*)(cur + (size_t)(s0+i)*32);
    float acc = 0.f;
    #pragma unroll
    for (int q=0;q<8;q++){ float4 v = cp[q]; acc += v.x*sh[q*4]+v.y*sh[q*4+1]+v.z*sh[q*4+2]+v.w*sh[q*4+3]; }
    evals[s0+i] = acc;
    lmax = fmaxf(lmax, acc);
  }
  red[tid] = lmax; __syncthreads();
  #pragma unroll
  for (int st=128; st>0; st>>=1){ if (tid<st) red[tid]=fmaxf(red[tid],red[tid+st]); __syncthreads(); }
  float mx = red[0]; __syncthreads();
  float lsum = 0.f;
  for (int i = tid; i < cnt; i += 256){
    float w = __expf(evals[s0+i]-mx);
    evals[s0+i] = w;
    lsum += w;
  }
  red[tid] = lsum; __syncthreads();
  #pragma unroll
  for (int st=128; st>0; st>>=1){ if (tid<st) red[tid]+=red[tid+st]; __syncthreads(); }
  float inv = 1.f/red[0]; __syncthreads();
  float rv[32];
  #pragma unroll
  for (int k=0;k<32;k++) rv[k]=0.f;
  for (int i = tid; i < cnt; i += 256){
    float a = evals[s0+i]*inv;
    const float4* cp = (const float4*)(cur + (size_t)(s0+i)*32);
    #pragma unroll
    for (int q=0;q<8;q++){ float4 v=cp[q]; rv[q*4]+=a*v.x; rv[q*4+1]+=a*v.y; rv[q*4+2]+=a*v.z; rv[q*4+3]+=a*v.w; }
  }
  #pragma unroll
  for (int k=0;k<32;k++){
    float v = rv[k];
    #pragma unroll
    for (int o=32;o>0;o>>=1) v += __shfl_down(v, o, 64);
    if ((tid&63)==0) atomicAdd(&srv[k], v);
  }
  __syncthreads();
  if (tid < 32) rvec[g*32+tid] = srv[tid];
}

// out[g] = relu([hs, rvec, ga] @ lin1 + b1) @ lin2 + b2
__global__ __launch_bounds__(128) void k_final(const float* __restrict__ hs, const float* __restrict__ rvec,
                                               const float* __restrict__ ga,
                                               const float* __restrict__ w1, const float* __restrict__ b1,
                                               const float* __restrict__ w2, const float* __restrict__ b2,
                                               float* __restrict__ out){
  __shared__ float sw1[2304]; __shared__ float sb1[32]; __shared__ float sw2[32];
  int tid = threadIdx.x;
  for (int i=tid;i<2304;i+=128) sw1[i]=w1[i];
  if (tid<32){ sb1[tid]=b1[tid]; sw2[tid]=w2[tid]; }
  __syncthreads();
  int g = tid;
  float hp[32], rp[32], gp[8];
  #pragma unroll
  for (int k=0;k<32;k++){ hp[k]=hs[g*32+k]; rp[k]=rvec[g*32+k]; }
  #pragma unroll
  for (int k=0;k<8;k++) gp[k]=ga[g*8+k];
  float o = b2[0];
  for (int j=0;j<32;j++){
    float acc = sb1[j];
    #pragma unroll
    for (int k=0;k<32;k++) acc += hp[k]*sw1[k*32+j];
    #pragma unroll
    for (int k=0;k<32;k++) acc += rp[k]*sw1[(32+k)*32+j];
    #pragma unroll
    for (int k=0;k<8;k++)  acc += gp[k]*sw1[(64+k)*32+j];
    o += fmaxf(acc,0.f)*sw2[j];
  }
  out[g] = o;
}

// ---------------- launch ----------------
extern "C" void kernel_launch(void* const* d_in, const int* in_sizes, int n_in,
                              void* d_out, int out_size, void* d_ws, size_t ws_size,
                              hipStream_t stream){
  (void)in_sizes; (void)n_in; (void)out_size;
  const float* x         = (const float*)d_in[0];
  const float* edge_attr = (const float*)d_in[1];
  const float* graph_attr= (const float*)d_in[2];
  const int*   eidx      = (const int*)d_in[3];
  const int*   batch     = (const int*)d_in[4];
  const float* lin0_w    = (const float*)d_in[5];
  const float* lin0_b    = (const float*)d_in[6];
  const float* nn1_w     = (const float*)d_in[7];
  const float* nn1_b     = (const float*)d_in[8];
  const float* nn2_w     = (const float*)d_in[9];
  const float* nn2_b     = (const float*)d_in[10];
  const float* root_w    = (const float*)d_in[11];
  const float* conv_b    = (const float*)d_in[12];
  const float* gru_wih   = (const float*)d_in[13];
  const float* gru_whh   = (const float*)d_in[14];
  const float* gru_bih   = (const float*)d_in[15];
  const float* gru_bhh   = (const float*)d_in[16];
  const float* lstm_wih  = (const float*)d_in[17];
  const float* lstm_whh  = (const float*)d_in[18];
  const float* lstm_bih  = (const float*)d_in[19];
  const float* lstm_bhh  = (const float*)d_in[20];
  const float* lin1_w    = (const float*)d_in[21];
  const float* lin1_b    = (const float*)d_in[22];
  const float* lin2_w    = (const float*)d_in[23];
  const float* lin2_b    = (const float*)d_in[24];
  const int* src = eidx;
  const int* dst = eidx + NED;

  char* pool = (ws_size >= kNeed) ? (char*)d_ws : (char*)g_fb;
  if (!pool) pool = (char*)d_ws;   // last resort
  size_t off = 0;
  auto alloc = [&](size_t bytes)->char* {
    char* p = pool + off; off += (bytes + 511) & ~(size_t)511; return p;
  };
  unsigned short* ew  = (unsigned short*)alloc((size_t)NED*1024*2);  // 409.6 MB, bf16 [e][o*32+d]
  float* H    = (float*)alloc((size_t)NED*128*4);                    // 102.4 MB
  float* cur  = (float*)alloc((size_t)NND*32*4);
  float* agg  = (float*)alloc((size_t)NND*32*4);
  float* deg  = (float*)alloc((size_t)NND*4);
  float* ev   = (float*)alloc((size_t)NND*4);
  float* nn2t = (float*)alloc(128*1024*4);
  float* b2t  = (float*)alloc(1024*4);
  float* hsb  = (float*)alloc(NG*32*4);
  float* csb  = (float*)alloc(NG*32*4);
  float* rvb  = (float*)alloc(NG*32*4);
  int*   counts = (int*)alloc(512);
  int*   startsb= (int*)alloc(512);

  hipMemsetAsync(counts, 0, 512, stream);
  hipMemsetAsync(deg, 0, (size_t)NND*4, stream);
  hipMemsetAsync(hsb, 0, NG*32*4, stream);
  hipMemsetAsync(csb, 0, NG*32*4, stream);
  hipMemsetAsync(rvb, 0, NG*32*4, stream);

  k_prep<<<512, 256, 0, stream>>>(nn2_w, nn2_b, nn2t, b2t);
  k_lin0<<<(NND+31)/32, 256, 0, stream>>>(x, lin0_w, lin0_b, cur);
  k_counts<<<(NND+255)/256, 256, 0, stream>>>(batch, counts);
  k_scan<<<1, 64, 0, stream>>>(counts, startsb);
  k_deg<<<(NED+255)/256, 256, 0, stream>>>(dst, deg);
  k_hidden<<<NED*32/256, 256, 0, stream>>>(edge_attr, nn1_w, nn1_b, H);
  k_gemm2<<<dim3(NED/64, 8), 256, 0, stream>>>(H, nn2t, b2t, ew);

  for (int it=0; it<3; ++it){
    hipMemsetAsync(agg, 0, (size_t)NND*32*4, stream);
    k_msg<<<NED*32/256, 256, 0, stream>>>(cur, ew, src, dst, agg);
    k_gru<<<NND/32, 256, 0, stream>>>(cur, agg, deg, root_w, conv_b,
                                      gru_wih, gru_whh, gru_bih, gru_bhh);
  }
  for (int st=0; st<3; ++st){
    k_lstm<<<1, 128, 0, stream>>>(hsb, csb, rvb, lstm_wih, lstm_whh, lstm_bih, lstm_bhh);
    k_attn<<<NG, 256, 0, stream>>>(cur, hsb, startsb, counts, ev, rvb);
  }
  k_final<<<1, 128, 0, stream>>>(hsb, rvb, graph_attr, lin1_w, lin1_b, lin2_w, lin2_b, (float*)d_out);
}

// Round 3
// 1542.037 us; speedup vs baseline: 2.7463x; 1.2918x over previous
//
#include <hip/hip_runtime.h>
#include <stdint.h>
#include <stddef.h>

// ---------------- problem constants ----------------
#define NND 100000   // nodes
#define NED 200000   // edges
#define NG  128      // graphs
// D=32, D_LIN=128, F_EDGE=16, F_GRAPH=8, MP_TIMES=3, STEPS=3

typedef unsigned short us8 __attribute__((ext_vector_type(8)));
typedef unsigned short us4v __attribute__((ext_vector_type(4)));
typedef short bf16x8 __attribute__((ext_vector_type(8)));
typedef float f32x4 __attribute__((ext_vector_type(4)));

__device__ __forceinline__ float bf2f(unsigned short u){
  union{unsigned u; float f;} v; v.u = ((unsigned)u)<<16; return v.f;
}
__device__ __forceinline__ unsigned short f2bf(float f){
  union{float f; unsigned u;} v; v.f = f;
  unsigned r = v.u + 0x7FFFu + ((v.u>>16)&1u);
  return (unsigned short)(r>>16);
}
__device__ __forceinline__ float sigm(float x){ return 1.f/(1.f+__expf(-x)); }
__device__ __forceinline__ float tanh_(float x){ return 2.f/(1.f+__expf(-2.f*x)) - 1.f; }

// ---------------- fallback workspace (ws_size may be < 540MB) ----------------
static const size_t kNeed = 540000000ull;
static void* g_fb = nullptr;
namespace {
struct FB { FB(){ if (hipMalloc(&g_fb, kNeed) != hipSuccess) g_fb = nullptr; } };
static FB g_fb_init;
}

// ---------------- kernels ----------------

// Btb[p][k] = bf16(nn2[k][d*32+o]) with p=o*32+d ; b2t[p] = b2[d*32+o]
__global__ __launch_bounds__(256) void k_prep(const float* __restrict__ nn2, const float* __restrict__ b2,
                                              unsigned short* __restrict__ Btb, float* __restrict__ b2t){
  int tid = blockIdx.x*256 + threadIdx.x;     // 128*1024 total
  int k = tid >> 10, p = tid & 1023;
  int q = ((p & 31) << 5) + (p >> 5);
  Btb[p*128 + k] = f2bf(nn2[(k << 10) + q]);
  if (k == 0) b2t[p] = b2[q];
}

// cur = relu(x @ lin0_w + lin0_b)  -- 32 lanes per node, lane j owns output j
__global__ __launch_bounds__(256) void k_lin0(const float* __restrict__ x, const float* __restrict__ w,
                                              const float* __restrict__ b, float* __restrict__ cur){
  __shared__ float sw[1024]; __shared__ float sb[32];
  __shared__ float sx[8][32];
  for (int i = threadIdx.x; i < 1024; i += 256) sw[i] = w[i];
  if (threadIdx.x < 32) sb[threadIdx.x] = b[threadIdx.x];
  __syncthreads();
  int ln = threadIdx.x >> 5, j = threadIdx.x & 31;
  for (int it = 0; it < 4; ++it){
    int n = (blockIdx.x*4 + it)*8 + ln;
    if (n >= NND) return;
    float xj = x[(size_t)n*32 + j];
    sx[ln][j] = xj;                       // wave-synchronous within the 32-lane group
    float acc = sb[j];
    #pragma unroll
    for (int d=0; d<32; d++) acc += sx[ln][d]*sw[d*32+j];
    cur[(size_t)n*32 + j] = fmaxf(acc, 0.f);
  }
}

// H = relu(edge_attr @ nn1 + b1)   [E,128] bf16; 32 threads/edge, 4 outputs each
__global__ __launch_bounds__(256) void k_hidden(const float* __restrict__ ea, const float* __restrict__ w1,
                                                const float* __restrict__ b1, unsigned short* __restrict__ H){
  __shared__ float sw[2048]; __shared__ float sb[128];
  for (int i=threadIdx.x;i<2048;i+=256) sw[i]=w1[i];
  if (threadIdx.x<128) sb[threadIdx.x]=b1[threadIdx.x];
  __syncthreads();
  int gid = blockIdx.x*256 + threadIdx.x;     // E*32 total, exact
  int e = gid >> 5, q = gid & 31;
  float a[16];
  const float4* ap = (const float4*)(ea + (size_t)e*16);
  #pragma unroll
  for (int i=0;i<4;i++){ float4 v=ap[i]; a[4*i]=v.x; a[4*i+1]=v.y; a[4*i+2]=v.z; a[4*i+3]=v.w; }
  float c0=sb[q*4], c1=sb[q*4+1], c2=sb[q*4+2], c3=sb[q*4+3];
  #pragma unroll
  for (int k=0;k<16;k++){
    float av=a[k]; const float* wr = &sw[k*128 + q*4];
    c0 += av*wr[0]; c1 += av*wr[1]; c2 += av*wr[2]; c3 += av*wr[3];
  }
  us4v o;
  o[0]=f2bf(fmaxf(c0,0.f)); o[1]=f2bf(fmaxf(c1,0.f));
  o[2]=f2bf(fmaxf(c2,0.f)); o[3]=f2bf(fmaxf(c3,0.f));
  *(us4v*)(H + (size_t)e*128 + q*4) = o;
}

// MFMA GEMM: ew[64e x 1024] = Hb[64e x 128k] @ Btb[1024p x 128k]^T + b2t, bf16 out.
// One block = 64 edges, loops 8 column-groups of 128. 4 waves: 2x2 of 32r x 64c.
__global__ __launch_bounds__(256) void k_gemm2m(const unsigned short* __restrict__ Hb,
                                                const unsigned short* __restrict__ Btb,
                                                const float* __restrict__ b2t,
                                                unsigned short* __restrict__ ew){
  __shared__ char smem[49152];           // sA 16KB | sB 32KB ; sC aliases sA
  char* sA = smem;
  char* sB = smem + 16384;
  int tid = threadIdx.x;
  int e0 = blockIdx.x * 64;
  int l = tid & 63, wv = tid >> 6;
  int wr = wv >> 1, wc = wv & 1;

  // stage A: 64 rows x 256B (XOR-swizzled), 4 passes of 16 rows
  {
    int r = tid >> 4, c16 = (tid & 15) * 16;
    #pragma unroll
    for (int pass = 0; pass < 4; ++pass){
      int row = pass*16 + r;
      bf16x8 v = *(const bf16x8*)(Hb + (size_t)(e0+row)*128 + (tid&15)*8);
      *(bf16x8*)(sA + row*256 + (c16 ^ ((row&7)<<4))) = v;
    }
  }
  __syncthreads();
  // A fragments to regs (sA free for reuse afterwards): [mi][ks]
  bf16x8 afr[2][4];
  #pragma unroll
  for (int mi=0; mi<2; ++mi){
    int row = wr*32 + mi*16 + (l & 15);
    #pragma unroll
    for (int ks=0; ks<4; ++ks){
      int kb = ks*64 + (l>>4)*16;
      afr[mi][ks] = *(bf16x8*)(sA + row*256 + (kb ^ ((row&7)<<4)));
    }
  }

  for (int cg = 0; cg < 8; ++cg){
    __syncthreads();                     // prev sB/sC consumers done
    // stage B strip: 128 p-rows x 256B (XOR-swizzled), 8 passes of 16 rows
    {
      int rr = tid >> 4, cc = tid & 15;
      #pragma unroll
      for (int pass = 0; pass < 8; ++pass){
        int p = pass*16 + rr;
        bf16x8 v = *(const bf16x8*)(Btb + (size_t)(cg*128 + p)*128 + cc*8);
        *(bf16x8*)(sB + p*256 + ((cc*16) ^ ((p&7)<<4))) = v;
      }
    }
    __syncthreads();
    float bz[4];
    #pragma unroll
    for (int ni=0; ni<4; ++ni) bz[ni] = b2t[cg*128 + wc*64 + ni*16 + (l&15)];
    f32x4 acc[2][4];
    #pragma unroll
    for (int mi=0; mi<2; ++mi)
      #pragma unroll
      for (int ni=0; ni<4; ++ni){
        f32x4 a; a[0]=bz[ni]; a[1]=bz[ni]; a[2]=bz[ni]; a[3]=bz[ni];
        acc[mi][ni] = a;
      }
    #pragma unroll
    for (int ks=0; ks<4; ++ks){
      bf16x8 bfr[4];
      #pragma unroll
      for (int ni=0; ni<4; ++ni){
        int p = wc*64 + ni*16 + (l&15);
        int kb = ks*64 + (l>>4)*16;
        bfr[ni] = *(bf16x8*)(sB + p*256 + (kb ^ ((p&7)<<4)));
      }
      #pragma unroll
      for (int mi=0; mi<2; ++mi)
        #pragma unroll
        for (int ni=0; ni<4; ++ni)
          acc[mi][ni] = __builtin_amdgcn_mfma_f32_16x16x32_bf16(afr[mi][ks], bfr[ni], acc[mi][ni], 0, 0, 0);
    }
    // C bounce: write bf16 into swizzled sC (=sA), then linear read + permuted coalesced store
    char* sC = sA;
    #pragma unroll
    for (int mi=0; mi<2; ++mi)
      #pragma unroll
      for (int ni=0; ni<4; ++ni){
        int colb = (wc*64 + ni*16 + (l&15)) * 2;
        #pragma unroll
        for (int q=0; q<4; ++q){
          int row = wr*32 + mi*16 + (l>>4)*4 + q;
          *(unsigned short*)(sC + row*256 + (colb ^ ((row&7)<<4))) = f2bf(acc[mi][ni][q]);
        }
      }
    __syncthreads();
    #pragma unroll
    for (int i=0; i<4; ++i){
      int L = i*4096 + tid*16;
      int row = L >> 8, bin = L & 255;
      int ub = bin ^ ((row&7)<<4);       // unswizzled byte-in-row
      bf16x8 v = *(bf16x8*)(sC + L);
      *(bf16x8*)(ew + (size_t)(e0+row)*1024 + cg*128 + (ub>>1)) = v;
    }
  }
}

__global__ __launch_bounds__(256) void k_counts(const int* __restrict__ batch, int* __restrict__ counts){
  int i = blockIdx.x*256 + threadIdx.x;
  if (i < NND) atomicAdd(&counts[batch[i]], 1);
}
__global__ void k_scan(const int* __restrict__ counts, int* __restrict__ starts){
  if (threadIdx.x == 0){ int s = 0; for (int g=0; g<NG; g++){ starts[g]=s; s+=counts[g]; } }
}
__global__ __launch_bounds__(256) void k_deg(const int* __restrict__ dst, float* __restrict__ deg){
  int e = blockIdx.x*256 + threadIdx.x;
  if (e < NED) atomicAdd(&deg[dst[e]], 1.f);
}

// msg[e,o] = sum_d cur[src[e],d]*ew[e][o*32+d];  atomicAdd into agg[dst,o].  32 lanes/edge.
__global__ __launch_bounds__(256) void k_msg(const float* __restrict__ cur, const unsigned short* __restrict__ ew,
                                             const int* __restrict__ src, const int* __restrict__ dst,
                                             float* __restrict__ agg){
  __shared__ float s_lds[8][32];
  int gid = blockIdx.x*256 + threadIdx.x;     // E*32 exact
  int e = gid >> 5, o = gid & 31, le = threadIdx.x >> 5;
  int s = src[e], t = dst[e];
  s_lds[le][o] = cur[(size_t)s*32 + o];
  __syncthreads();
  float acc = 0.f;
  const unsigned short* er = ew + (size_t)e*1024 + o*32;
  const float* sr = s_lds[le];
  #pragma unroll
  for (int d0=0; d0<32; d0+=8){
    us8 u = *(const us8*)(er + d0);
    #pragma unroll
    for (int j=0;j<8;j++) acc += bf2f(u[j]) * sr[d0+j];
  }
  atomicAdd(&agg[(size_t)t*32 + o], acc);
}

// m = relu(cur@root + agg/deg + cb); GRU(h=cur, in=m) -> cur.
// 32 lanes per node (lane j owns channel j); 8 nodes per 256-thr block-slice, 4 slices.
__global__ __launch_bounds__(256) void k_gru(float* __restrict__ cur, const float* __restrict__ agg,
                                             const float* __restrict__ deg,
                                             const float* __restrict__ root_w, const float* __restrict__ conv_b,
                                             const float* __restrict__ wih, const float* __restrict__ whh,
                                             const float* __restrict__ bih, const float* __restrict__ bhh){
  __shared__ float s_root[1024], s_wih[3072], s_whh[3072], s_cb[32], s_bih[96], s_bhh[96];
  __shared__ float s_c[8][32], s_m[8][32];
  for (int i=threadIdx.x;i<1024;i+=256) s_root[i]=root_w[i];
  for (int i=threadIdx.x;i<3072;i+=256){ s_wih[i]=wih[i]; s_whh[i]=whh[i]; }
  if (threadIdx.x<32) s_cb[threadIdx.x]=conv_b[threadIdx.x];
  if (threadIdx.x<96){ s_bih[threadIdx.x]=bih[threadIdx.x]; s_bhh[threadIdx.x]=bhh[threadIdx.x]; }
  __syncthreads();
  int ln = threadIdx.x >> 5, j = threadIdx.x & 31;
  for (int it = 0; it < 4; ++it){
    int n = (blockIdx.x*4 + it)*8 + ln;
    float c_j = cur[(size_t)n*32 + j];
    float a_j = agg[(size_t)n*32 + j];
    s_c[ln][j] = c_j;
    float idg = 1.f / fmaxf(deg[n], 1.f);
    float acc = s_cb[j] + a_j*idg;
    #pragma unroll
    for (int d=0; d<32; d++) acc += s_c[ln][d]*s_root[d*32+j];
    float m_j = fmaxf(acc, 0.f);
    s_m[ln][j] = m_j;
    float gr = s_bih[j], gz = s_bih[32+j], gn = s_bih[64+j];
    float hr = s_bhh[j], hz = s_bhh[32+j], hh = s_bhh[64+j];
    #pragma unroll
    for (int k=0;k<32;k++){
      float mk = s_m[ln][k], ck = s_c[ln][k];
      gr += mk*s_wih[k*96+j];
      gz += mk*s_wih[k*96+32+j];
      gn += mk*s_wih[k*96+64+j];
      hr += ck*s_whh[k*96+j];
      hz += ck*s_whh[k*96+32+j];
      hh += ck*s_whh[k*96+64+j];
    }
    float r = sigm(gr+hr);
    float z = sigm(gz+hz);
    float nnv = tanh_(gn + r*hh);
    cur[(size_t)n*32 + j] = (1.f-z)*nnv + z*c_j;
  }
}

// LSTM over 128 graphs (single block). hs/cs updated in place; reads prev hs + rvec (= q_star).
__global__ __launch_bounds__(128) void k_lstm(float* __restrict__ hs, float* __restrict__ cs,
                                              const float* __restrict__ rvec,
                                              const float* __restrict__ wih, const float* __restrict__ whh,
                                              const float* __restrict__ bih, const float* __restrict__ bhh){
  __shared__ float swih[8192];   // 64x128
  __shared__ float swhh[4096];   // 32x128
  __shared__ float sb[128];
  int tid = threadIdx.x;
  for (int i=tid;i<8192;i+=128) swih[i]=wih[i];
  for (int i=tid;i<4096;i+=128) swhh[i]=whh[i];
  sb[tid] = bih[tid] + bhh[tid];
  __syncthreads();
  int g = tid;
  float hp[32], rp[32], cp[32];
  #pragma unroll
  for (int k=0;k<32;k++){ hp[k]=hs[g*32+k]; rp[k]=rvec[g*32+k]; cp[k]=cs[g*32+k]; }
  for (int j=0;j<32;j++){
    float gI=sb[j], gF=sb[32+j], gG=sb[64+j], gO=sb[96+j];
    #pragma unroll
    for (int k=0;k<32;k++){
      float h=hp[k], r=rp[k];
      gI += h*(swih[k*128+j]    + swhh[k*128+j])    + r*swih[(32+k)*128+j];
      gF += h*(swih[k*128+32+j] + swhh[k*128+32+j]) + r*swih[(32+k)*128+32+j];
      gG += h*(swih[k*128+64+j] + swhh[k*128+64+j]) + r*swih[(32+k)*128+64+j];
      gO += h*(swih[k*128+96+j] + swhh[k*128+96+j]) + r*swih[(32+k)*128+96+j];
    }
    float cn = sigm(gF)*cp[j] + sigm(gI)*tanh_(gG);
    cs[g*32+j] = cn;
    hs[g*32+j] = sigm(gO)*tanh_(cn);
  }
}

// Per-graph segment softmax attention + weighted sum (batch sorted -> contiguous segments)
__global__ __launch_bounds__(256) void k_attn(const float* __restrict__ cur, const float* __restrict__ hs,
                                              const int* __restrict__ starts, const int* __restrict__ counts,
                                              float* __restrict__ evals, float* __restrict__ rvec){
  int g = blockIdx.x;
  int s0 = starts[g], cnt = counts[g];
  int tid = threadIdx.x;
  __shared__ float red[256];
  __shared__ float sh[32];
  __shared__ float srv[32];
  if (tid < 32){ sh[tid] = hs[g*32+tid]; srv[tid] = 0.f; }
  __syncthreads();
  float lmax = -3.4e38f;
  for (int i = tid; i < cnt; i += 256){
    const float4* cp = (const float4*)(cur + (size_t)(s0+i)*32);
    float acc = 0.f;
    #pragma unroll
    for (int q=0;q<8;q++){ float4 v = cp[q]; acc += v.x*sh[q*4]+v.y*sh[q*4+1]+v.z*sh[q*4+2]+v.w*sh[q*4+3]; }
    evals[s0+i] = acc;
    lmax = fmaxf(lmax, acc);
  }
  red[tid] = lmax; __syncthreads();
  #pragma unroll
  for (int st=128; st>0; st>>=1){ if (tid<st) red[tid]=fmaxf(red[tid],red[tid+st]); __syncthreads(); }
  float mx = red[0]; __syncthreads();
  float lsum = 0.f;
  for (int i = tid; i < cnt; i += 256){
    float w = __expf(evals[s0+i]-mx);
    evals[s0+i] = w;
    lsum += w;
  }
  red[tid] = lsum; __syncthreads();
  #pragma unroll
  for (int st=128; st>0; st>>=1){ if (tid<st) red[tid]+=red[tid+st]; __syncthreads(); }
  float inv = 1.f/red[0]; __syncthreads();
  float rv[32];
  #pragma unroll
  for (int k=0;k<32;k++) rv[k]=0.f;
  for (int i = tid; i < cnt; i += 256){
    float a = evals[s0+i]*inv;
    const float4* cp = (const float4*)(cur + (size_t)(s0+i)*32);
    #pragma unroll
    for (int q=0;q<8;q++){ float4 v=cp[q]; rv[q*4]+=a*v.x; rv[q*4+1]+=a*v.y; rv[q*4+2]+=a*v.z; rv[q*4+3]+=a*v.w; }
  }
  #pragma unroll
  for (int k=0;k<32;k++){
    float v = rv[k];
    #pragma unroll
    for (int o=32;o>0;o>>=1) v += __shfl_down(v, o, 64);
    if ((tid&63)==0) atomicAdd(&srv[k], v);
  }
  __syncthreads();
  if (tid < 32) rvec[g*32+tid] = srv[tid];
}

// out[g] = relu([hs, rvec, ga] @ lin1 + b1) @ lin2 + b2
__global__ __launch_bounds__(128) void k_final(const float* __restrict__ hs, const float* __restrict__ rvec,
                                               const float* __restrict__ ga,
                                               const float* __restrict__ w1, const float* __restrict__ b1,
                                               const float* __restrict__ w2, const float* __restrict__ b2,
                                               float* __restrict__ out){
  __shared__ float sw1[2304]; __shared__ float sb1[32]; __shared__ float sw2[32];
  int tid = threadIdx.x;
  for (int i=tid;i<2304;i+=128) sw1[i]=w1[i];
  if (tid<32){ sb1[tid]=b1[tid]; sw2[tid]=w2[tid]; }
  __syncthreads();
  int g = tid;
  float hp[32], rp[32], gp[8];
  #pragma unroll
  for (int k=0;k<32;k++){ hp[k]=hs[g*32+k]; rp[k]=rvec[g*32+k]; }
  #pragma unroll
  for (int k=0;k<8;k++) gp[k]=ga[g*8+k];
  float o = b2[0];
  for (int j=0;j<32;j++){
    float acc = sb1[j];
    #pragma unroll
    for (int k=0;k<32;k++) acc += hp[k]*sw1[k*32+j];
    #pragma unroll
    for (int k=0;k<32;k++) acc += rp[k]*sw1[(32+k)*32+j];
    #pragma unroll
    for (int k=0;k<8;k++)  acc += gp[k]*sw1[(64+k)*32+j];
    o += fmaxf(acc,0.f)*sw2[j];
  }
  out[g] = o;
}

// ---------------- launch ----------------
extern "C" void kernel_launch(void* const* d_in, const int* in_sizes, int n_in,
                              void* d_out, int out_size, void* d_ws, size_t ws_size,
                              hipStream_t stream){
  (void)in_sizes; (void)n_in; (void)out_size;
  const float* x         = (const float*)d_in[0];
  const float* edge_attr = (const float*)d_in[1];
  const float* graph_attr= (const float*)d_in[2];
  const int*   eidx      = (const int*)d_in[3];
  const int*   batch     = (const int*)d_in[4];
  const float* lin0_w    = (const float*)d_in[5];
  const float* lin0_b    = (const float*)d_in[6];
  const float* nn1_w     = (const float*)d_in[7];
  const float* nn1_b     = (const float*)d_in[8];
  const float* nn2_w     = (const float*)d_in[9];
  const float* nn2_b     = (const float*)d_in[10];
  const float* root_w    = (const float*)d_in[11];
  const float* conv_b    = (const float*)d_in[12];
  const float* gru_wih   = (const float*)d_in[13];
  const float* gru_whh   = (const float*)d_in[14];
  const float* gru_bih   = (const float*)d_in[15];
  const float* gru_bhh   = (const float*)d_in[16];
  const float* lstm_wih  = (const float*)d_in[17];
  const float* lstm_whh  = (const float*)d_in[18];
  const float* lstm_bih  = (const float*)d_in[19];
  const float* lstm_bhh  = (const float*)d_in[20];
  const float* lin1_w    = (const float*)d_in[21];
  const float* lin1_b    = (const float*)d_in[22];
  const float* lin2_w    = (const float*)d_in[23];
  const float* lin2_b    = (const float*)d_in[24];
  const int* src = eidx;
  const int* dst = eidx + NED;

  char* pool = (ws_size >= kNeed) ? (char*)d_ws : (char*)g_fb;
  if (!pool) pool = (char*)d_ws;   // last resort
  size_t off = 0;
  auto alloc = [&](size_t bytes)->char* {
    char* p = pool + off; off += (bytes + 511) & ~(size_t)511; return p;
  };
  unsigned short* ew  = (unsigned short*)alloc((size_t)NED*1024*2);  // 409.6 MB, bf16 [e][o*32+d]
  unsigned short* H   = (unsigned short*)alloc((size_t)NED*128*2);   // 51.2 MB, bf16
  float* cur  = (float*)alloc((size_t)NND*32*4);
  float* agg  = (float*)alloc((size_t)NND*32*4);
  float* deg  = (float*)alloc((size_t)NND*4);
  float* ev   = (float*)alloc((size_t)NND*4);
  unsigned short* Btb = (unsigned short*)alloc(1024*128*2);          // bf16 [p][k]
  float* b2t  = (float*)alloc(1024*4);
  float* hsb  = (float*)alloc(NG*32*4);
  float* csb  = (float*)alloc(NG*32*4);
  float* rvb  = (float*)alloc(NG*32*4);
  int*   counts = (int*)alloc(512);
  int*   startsb= (int*)alloc(512);

  hipMemsetAsync(counts, 0, 512, stream);
  hipMemsetAsync(deg, 0, (size_t)NND*4, stream);
  hipMemsetAsync(hsb, 0, NG*32*4, stream);
  hipMemsetAsync(csb, 0, NG*32*4, stream);
  hipMemsetAsync(rvb, 0, NG*32*4, stream);

  k_prep<<<512, 256, 0, stream>>>(nn2_w, nn2_b, Btb, b2t);
  k_lin0<<<(NND+31)/32, 256, 0, stream>>>(x, lin0_w, lin0_b, cur);
  k_counts<<<(NND+255)/256, 256, 0, stream>>>(batch, counts);
  k_scan<<<1, 64, 0, stream>>>(counts, startsb);
  k_deg<<<(NED+255)/256, 256, 0, stream>>>(dst, deg);
  k_hidden<<<NED*32/256, 256, 0, stream>>>(edge_attr, nn1_w, nn1_b, H);
  k_gemm2m<<<NED/64, 256, 0, stream>>>(H, Btb, b2t, ew);

  for (int it=0; it<3; ++it){
    hipMemsetAsync(agg, 0, (size_t)NND*32*4, stream);
    k_msg<<<NED*32/256, 256, 0, stream>>>(cur, ew, src, dst, agg);
    k_gru<<<NND/32, 256, 0, stream>>>(cur, agg, deg, root_w, conv_b,
                                      gru_wih, gru_whh, gru_bih, gru_bhh);
  }
  for (int st=0; st<3; ++st){
    k_lstm<<<1, 128, 0, stream>>>(hsb, csb, rvb, lstm_wih, lstm_whh, lstm_bih, lstm_bhh);
    k_attn<<<NG, 256, 0, stream>>>(cur, hsb, startsb, counts, ev, rvb);
  }
  k_final<<<1, 128, 0, stream>>>(hsb, rvb, graph_attr, lin1_w, lin1_b, lin2_w, lin2_b, (float*)d_out);
}

// Round 4
// 1258.393 us; speedup vs baseline: 3.3654x; 1.2254x over previous
//
#include <hip/hip_runtime.h>
#include <stdint.h>
#include <stddef.h>

// ---------------- problem constants ----------------
#define NND 100000   // nodes
#define NED 200000   // edges
#define NG  128      // graphs
// D=32, D_LIN=128, F_EDGE=16, F_GRAPH=8, MP_TIMES=3, STEPS=3

typedef unsigned short us8 __attribute__((ext_vector_type(8)));
typedef unsigned short us4v __attribute__((ext_vector_type(4)));
typedef short bf16x8 __attribute__((ext_vector_type(8)));
typedef float f32x4 __attribute__((ext_vector_type(4)));

__device__ __forceinline__ float bf2f(unsigned short u){
  union{unsigned u; float f;} v; v.u = ((unsigned)u)<<16; return v.f;
}
__device__ __forceinline__ unsigned short f2bf(float f){
  union{float f; unsigned u;} v; v.f = f;
  unsigned r = v.u + 0x7FFFu + ((v.u>>16)&1u);
  return (unsigned short)(r>>16);
}
__device__ __forceinline__ float sigm(float x){ return 1.f/(1.f+__expf(-x)); }
__device__ __forceinline__ float tanh_(float x){ return 2.f/(1.f+__expf(-2.f*x)) - 1.f; }

// ---------------- fallback workspace (ws_size may be < 540MB) ----------------
static const size_t kNeed = 540000000ull;
static void* g_fb = nullptr;
namespace {
struct FB { FB(){ if (hipMalloc(&g_fb, kNeed) != hipSuccess) g_fb = nullptr; } };
static FB g_fb_init;
}

// ---------------- kernels ----------------

// Btb[p][k] = bf16(nn2[k][d*32+o]) with p=o*32+d ; b2t[p] = b2[d*32+o]
__global__ __launch_bounds__(256) void k_prep(const float* __restrict__ nn2, const float* __restrict__ b2,
                                              unsigned short* __restrict__ Btb, float* __restrict__ b2t){
  int tid = blockIdx.x*256 + threadIdx.x;     // 128*1024 total
  int k = tid >> 10, p = tid & 1023;
  int q = ((p & 31) << 5) + (p >> 5);
  Btb[p*128 + k] = f2bf(nn2[(k << 10) + q]);
  if (k == 0) b2t[p] = b2[q];
}

// starts/counts via binary search over sorted batch (one block, 128 threads)
__global__ __launch_bounds__(128) void k_starts(const int* __restrict__ batch,
                                                int* __restrict__ starts, int* __restrict__ counts){
  __shared__ int s[129];
  int g = threadIdx.x;
  int lo = 0, hi = NND;
  while (lo < hi){ int mid = (lo + hi) >> 1; if (batch[mid] < g) lo = mid + 1; else hi = mid; }
  s[g] = lo;
  if (g == 0) s[128] = NND;
  __syncthreads();
  starts[g] = s[g];
  counts[g] = s[g+1] - s[g];
}

// cur = relu(x @ lin0_w + lin0_b)  -- 32 lanes per node, lane j owns output j
__global__ __launch_bounds__(256) void k_lin0(const float* __restrict__ x, const float* __restrict__ w,
                                              const float* __restrict__ b, float* __restrict__ cur){
  __shared__ float sw[1024]; __shared__ float sb[32];
  __shared__ float sx[8][32];
  for (int i = threadIdx.x; i < 1024; i += 256) sw[i] = w[i];
  if (threadIdx.x < 32) sb[threadIdx.x] = b[threadIdx.x];
  __syncthreads();
  int ln = threadIdx.x >> 5, j = threadIdx.x & 31;
  for (int it = 0; it < 4; ++it){
    int n = (blockIdx.x*4 + it)*8 + ln;
    if (n >= NND) return;
    float xj = x[(size_t)n*32 + j];
    sx[ln][j] = xj;                       // wave-synchronous within the 32-lane group
    float acc = sb[j];
    #pragma unroll
    for (int d=0; d<32; d++) acc += sx[ln][d]*sw[d*32+j];
    cur[(size_t)n*32 + j] = fmaxf(acc, 0.f);
  }
}

// H = relu(edge_attr @ nn1 + b1)   [E,128] bf16; 32 threads/edge, 4 outputs each
__global__ __launch_bounds__(256) void k_hidden(const float* __restrict__ ea, const float* __restrict__ w1,
                                                const float* __restrict__ b1, unsigned short* __restrict__ H){
  __shared__ float sw[2048]; __shared__ float sb[128];
  for (int i=threadIdx.x;i<2048;i+=256) sw[i]=w1[i];
  if (threadIdx.x<128) sb[threadIdx.x]=b1[threadIdx.x];
  __syncthreads();
  int gid = blockIdx.x*256 + threadIdx.x;     // E*32 total, exact
  int e = gid >> 5, q = gid & 31;
  float a[16];
  const float4* ap = (const float4*)(ea + (size_t)e*16);
  #pragma unroll
  for (int i=0;i<4;i++){ float4 v=ap[i]; a[4*i]=v.x; a[4*i+1]=v.y; a[4*i+2]=v.z; a[4*i+3]=v.w; }
  float c0=sb[q*4], c1=sb[q*4+1], c2=sb[q*4+2], c3=sb[q*4+3];
  #pragma unroll
  for (int k=0;k<16;k++){
    float av=a[k]; const float* wr = &sw[k*128 + q*4];
    c0 += av*wr[0]; c1 += av*wr[1]; c2 += av*wr[2]; c3 += av*wr[3];
  }
  us4v o;
  o[0]=f2bf(fmaxf(c0,0.f)); o[1]=f2bf(fmaxf(c1,0.f));
  o[2]=f2bf(fmaxf(c2,0.f)); o[3]=f2bf(fmaxf(c3,0.f));
  *(us4v*)(H + (size_t)e*128 + q*4) = o;
}

// MFMA GEMM: ew[64e x 1024] = Hb[64e x 128k] @ Btb[1024p x 128k]^T + b2t, bf16 out.
// One block = 64 edges, loops 8 column-groups of 128. 4 waves: 2x2 of 32r x 64c.
__global__ __launch_bounds__(256) void k_gemm2m(const unsigned short* __restrict__ Hb,
                                                const unsigned short* __restrict__ Btb,
                                                const float* __restrict__ b2t,
                                                unsigned short* __restrict__ ew){
  __shared__ char smem[49152];           // sA 16KB | sB 32KB ; sC aliases sA
  char* sA = smem;
  char* sB = smem + 16384;
  int tid = threadIdx.x;
  int e0 = blockIdx.x * 64;
  int l = tid & 63, wv = tid >> 6;
  int wr = wv >> 1, wc = wv & 1;

  // stage A: 64 rows x 256B (XOR-swizzled), 4 passes of 16 rows
  {
    int r = tid >> 4, c16 = (tid & 15) * 16;
    #pragma unroll
    for (int pass = 0; pass < 4; ++pass){
      int row = pass*16 + r;
      bf16x8 v = *(const bf16x8*)(Hb + (size_t)(e0+row)*128 + (tid&15)*8);
      *(bf16x8*)(sA + row*256 + (c16 ^ ((row&7)<<4))) = v;
    }
  }
  __syncthreads();
  // A fragments to regs (sA free for reuse afterwards): [mi][ks]
  bf16x8 afr[2][4];
  #pragma unroll
  for (int mi=0; mi<2; ++mi){
    int row = wr*32 + mi*16 + (l & 15);
    #pragma unroll
    for (int ks=0; ks<4; ++ks){
      int kb = ks*64 + (l>>4)*16;
      afr[mi][ks] = *(bf16x8*)(sA + row*256 + (kb ^ ((row&7)<<4)));
    }
  }

  for (int cg = 0; cg < 8; ++cg){
    __syncthreads();                     // prev sB/sC consumers done
    // stage B strip: 128 p-rows x 256B (XOR-swizzled), 8 passes of 16 rows
    {
      int rr = tid >> 4, cc = tid & 15;
      #pragma unroll
      for (int pass = 0; pass < 8; ++pass){
        int p = pass*16 + rr;
        bf16x8 v = *(const bf16x8*)(Btb + (size_t)(cg*128 + p)*128 + cc*8);
        *(bf16x8*)(sB + p*256 + ((cc*16) ^ ((p&7)<<4))) = v;
      }
    }
    __syncthreads();
    float bz[4];
    #pragma unroll
    for (int ni=0; ni<4; ++ni) bz[ni] = b2t[cg*128 + wc*64 + ni*16 + (l&15)];
    f32x4 acc[2][4];
    #pragma unroll
    for (int mi=0; mi<2; ++mi)
      #pragma unroll
      for (int ni=0; ni<4; ++ni){
        f32x4 a; a[0]=bz[ni]; a[1]=bz[ni]; a[2]=bz[ni]; a[3]=bz[ni];
        acc[mi][ni] = a;
      }
    #pragma unroll
    for (int ks=0; ks<4; ++ks){
      bf16x8 bfr[4];
      #pragma unroll
      for (int ni=0; ni<4; ++ni){
        int p = wc*64 + ni*16 + (l&15);
        int kb = ks*64 + (l>>4)*16;
        bfr[ni] = *(bf16x8*)(sB + p*256 + (kb ^ ((p&7)<<4)));
      }
      #pragma unroll
      for (int mi=0; mi<2; ++mi)
        #pragma unroll
        for (int ni=0; ni<4; ++ni)
          acc[mi][ni] = __builtin_amdgcn_mfma_f32_16x16x32_bf16(afr[mi][ks], bfr[ni], acc[mi][ni], 0, 0, 0);
    }
    // C bounce: write bf16 into swizzled sC (=sA), then linear read + permuted coalesced store
    char* sC = sA;
    #pragma unroll
    for (int mi=0; mi<2; ++mi)
      #pragma unroll
      for (int ni=0; ni<4; ++ni){
        int colb = (wc*64 + ni*16 + (l&15)) * 2;
        #pragma unroll
        for (int q=0; q<4; ++q){
          int row = wr*32 + mi*16 + (l>>4)*4 + q;
          *(unsigned short*)(sC + row*256 + (colb ^ ((row&7)<<4))) = f2bf(acc[mi][ni][q]);
        }
      }
    __syncthreads();
    #pragma unroll
    for (int i=0; i<4; ++i){
      int L = i*4096 + tid*16;
      int row = L >> 8, bin = L & 255;
      int ub = bin ^ ((row&7)<<4);       // unswizzled byte-in-row
      bf16x8 v = *(bf16x8*)(sC + L);
      *(bf16x8*)(ew + (size_t)(e0+row)*1024 + cg*128 + (ub>>1)) = v;
    }
  }
}

__global__ __launch_bounds__(256) void k_deg(const int* __restrict__ dst, float* __restrict__ deg){
  int e = blockIdx.x*256 + threadIdx.x;
  if (e < NED) atomicAdd(&deg[dst[e]], 1.f);
}

// msg[e,o] = sum_d cur[src[e],d]*ew[e][o*32+d];  atomicAdd into agg[dst,o].  32 lanes/edge.
__global__ __launch_bounds__(256) void k_msg(const float* __restrict__ cur, const unsigned short* __restrict__ ew,
                                             const int* __restrict__ src, const int* __restrict__ dst,
                                             float* __restrict__ agg){
  __shared__ float s_lds[8][32];
  int gid = blockIdx.x*256 + threadIdx.x;     // E*32 exact
  int e = gid >> 5, o = gid & 31, le = threadIdx.x >> 5;
  int s = src[e], t = dst[e];
  s_lds[le][o] = cur[(size_t)s*32 + o];
  __syncthreads();
  float acc = 0.f;
  const unsigned short* er = ew + (size_t)e*1024 + o*32;
  const float* sr = s_lds[le];
  #pragma unroll
  for (int d0=0; d0<32; d0+=8){
    us8 u = *(const us8*)(er + d0);
    #pragma unroll
    for (int j=0;j<8;j++) acc += bf2f(u[j]) * sr[d0+j];
  }
  atomicAdd(&agg[(size_t)t*32 + o], acc);
}

// m = relu(cur@root + agg/deg + cb); GRU(h=cur, in=m) -> cur. Zeroes agg after read.
// 32 lanes per node (lane j owns channel j); 8 nodes per 256-thr block-slice, 4 slices.
__global__ __launch_bounds__(256) void k_gru(float* __restrict__ cur, float* __restrict__ agg,
                                             const float* __restrict__ deg,
                                             const float* __restrict__ root_w, const float* __restrict__ conv_b,
                                             const float* __restrict__ wih, const float* __restrict__ whh,
                                             const float* __restrict__ bih, const float* __restrict__ bhh){
  __shared__ float s_root[1024], s_wih[3072], s_whh[3072], s_cb[32], s_bih[96], s_bhh[96];
  __shared__ float s_c[8][32], s_m[8][32];
  for (int i=threadIdx.x;i<1024;i+=256) s_root[i]=root_w[i];
  for (int i=threadIdx.x;i<3072;i+=256){ s_wih[i]=wih[i]; s_whh[i]=whh[i]; }
  if (threadIdx.x<32) s_cb[threadIdx.x]=conv_b[threadIdx.x];
  if (threadIdx.x<96){ s_bih[threadIdx.x]=bih[threadIdx.x]; s_bhh[threadIdx.x]=bhh[threadIdx.x]; }
  __syncthreads();
  int ln = threadIdx.x >> 5, j = threadIdx.x & 31;
  for (int it = 0; it < 4; ++it){
    int n = (blockIdx.x*4 + it)*8 + ln;
    float c_j = cur[(size_t)n*32 + j];
    float a_j = agg[(size_t)n*32 + j];
    agg[(size_t)n*32 + j] = 0.f;       // re-zero for next k_msg pass (same traffic as memset)
    s_c[ln][j] = c_j;
    float idg = 1.f / fmaxf(deg[n], 1.f);
    float acc = s_cb[j] + a_j*idg;
    #pragma unroll
    for (int d=0; d<32; d++) acc += s_c[ln][d]*s_root[d*32+j];
    float m_j = fmaxf(acc, 0.f);
    s_m[ln][j] = m_j;
    float gr = s_bih[j], gz = s_bih[32+j], gn = s_bih[64+j];
    float hr = s_bhh[j], hz = s_bhh[32+j], hh = s_bhh[64+j];
    #pragma unroll
    for (int k=0;k<32;k++){
      float mk = s_m[ln][k], ck = s_c[ln][k];
      gr += mk*s_wih[k*96+j];
      gz += mk*s_wih[k*96+32+j];
      gn += mk*s_wih[k*96+64+j];
      hr += ck*s_whh[k*96+j];
      hz += ck*s_whh[k*96+32+j];
      hh += ck*s_whh[k*96+64+j];
    }
    float r = sigm(gr+hr);
    float z = sigm(gz+hz);
    float nnv = tanh_(gn + r*hh);
    cur[(size_t)n*32 + j] = (1.f-z)*nnv + z*c_j;
  }
}

// LSTM over 128 graphs (single block). hs/cs updated in place; reads prev hs + rvec (= q_star).
__global__ __launch_bounds__(128) void k_lstm(float* __restrict__ hs, float* __restrict__ cs,
                                              const float* __restrict__ rvec,
                                              const float* __restrict__ wih, const float* __restrict__ whh,
                                              const float* __restrict__ bih, const float* __restrict__ bhh){
  __shared__ float swih[8192];   // 64x128
  __shared__ float swhh[4096];   // 32x128
  __shared__ float sb[128];
  int tid = threadIdx.x;
  for (int i=tid;i<8192;i+=128) swih[i]=wih[i];
  for (int i=tid;i<4096;i+=128) swhh[i]=whh[i];
  sb[tid] = bih[tid] + bhh[tid];
  __syncthreads();
  int g = tid;
  float hp[32], rp[32], cp[32];
  #pragma unroll
  for (int k=0;k<32;k++){ hp[k]=hs[g*32+k]; rp[k]=rvec[g*32+k]; cp[k]=cs[g*32+k]; }
  for (int j=0;j<32;j++){
    float gI=sb[j], gF=sb[32+j], gG=sb[64+j], gO=sb[96+j];
    #pragma unroll
    for (int k=0;k<32;k++){
      float h=hp[k], r=rp[k];
      gI += h*(swih[k*128+j]    + swhh[k*128+j])    + r*swih[(32+k)*128+j];
      gF += h*(swih[k*128+32+j] + swhh[k*128+32+j]) + r*swih[(32+k)*128+32+j];
      gG += h*(swih[k*128+64+j] + swhh[k*128+64+j]) + r*swih[(32+k)*128+64+j];
      gO += h*(swih[k*128+96+j] + swhh[k*128+96+j]) + r*swih[(32+k)*128+96+j];
    }
    float cn = sigm(gF)*cp[j] + sigm(gI)*tanh_(gG);
    cs[g*32+j] = cn;
    hs[g*32+j] = sigm(gO)*tanh_(cn);
  }
}

// Per-graph segment softmax attention + weighted sum (batch sorted -> contiguous segments)
__global__ __launch_bounds__(256) void k_attn(const float* __restrict__ cur, const float* __restrict__ hs,
                                              const int* __restrict__ starts, const int* __restrict__ counts,
                                              float* __restrict__ evals, float* __restrict__ rvec){
  int g = blockIdx.x;
  int s0 = starts[g], cnt = counts[g];
  int tid = threadIdx.x;
  __shared__ float red[256];
  __shared__ float sh[32];
  __shared__ float srv[32];
  if (tid < 32){ sh[tid] = hs[g*32+tid]; srv[tid] = 0.f; }
  __syncthreads();
  float lmax = -3.4e38f;
  for (int i = tid; i < cnt; i += 256){
    const float4* cp = (const float4*)(cur + (size_t)(s0+i)*32);
    float acc = 0.f;
    #pragma unroll
    for (int q=0;q<8;q++){ float4 v = cp[q]; acc += v.x*sh[q*4]+v.y*sh[q*4+1]+v.z*sh[q*4+2]+v.w*sh[q*4+3]; }
    evals[s0+i] = acc;
    lmax = fmaxf(lmax, acc);
  }
  red[tid] = lmax; __syncthreads();
  #pragma unroll
  for (int st=128; st>0; st>>=1){ if (tid<st) red[tid]=fmaxf(red[tid],red[tid+st]); __syncthreads(); }
  float mx = red[0]; __syncthreads();
  float lsum = 0.f;
  for (int i = tid; i < cnt; i += 256){
    float w = __expf(evals[s0+i]-mx);
    evals[s0+i] = w;
    lsum += w;
  }
  red[tid] = lsum; __syncthreads();
  #pragma unroll
  for (int st=128; st>0; st>>=1){ if (tid<st) red[tid]+=red[tid+st]; __syncthreads(); }
  float inv = 1.f/red[0]; __syncthreads();
  float rv[32];
  #pragma unroll
  for (int k=0;k<32;k++) rv[k]=0.f;
  for (int i = tid; i < cnt; i += 256){
    float a = evals[s0+i]*inv;
    const float4* cp = (const float4*)(cur + (size_t)(s0+i)*32);
    #pragma unroll
    for (int q=0;q<8;q++){ float4 v=cp[q]; rv[q*4]+=a*v.x; rv[q*4+1]+=a*v.y; rv[q*4+2]+=a*v.z; rv[q*4+3]+=a*v.w; }
  }
  #pragma unroll
  for (int k=0;k<32;k++){
    float v = rv[k];
    #pragma unroll
    for (int o=32;o>0;o>>=1) v += __shfl_down(v, o, 64);
    if ((tid&63)==0) atomicAdd(&srv[k], v);
  }
  __syncthreads();
  if (tid < 32) rvec[g*32+tid] = srv[tid];
}

// out[g] = relu([hs, rvec, ga] @ lin1 + b1) @ lin2 + b2
__global__ __launch_bounds__(128) void k_final(const float* __restrict__ hs, const float* __restrict__ rvec,
                                               const float* __restrict__ ga,
                                               const float* __restrict__ w1, const float* __restrict__ b1,
                                               const float* __restrict__ w2, const float* __restrict__ b2,
                                               float* __restrict__ out){
  __shared__ float sw1[2304]; __shared__ float sb1[32]; __shared__ float sw2[32];
  int tid = threadIdx.x;
  for (int i=tid;i<2304;i+=128) sw1[i]=w1[i];
  if (tid<32){ sb1[tid]=b1[tid]; sw2[tid]=w2[tid]; }
  __syncthreads();
  int g = tid;
  float hp[32], rp[32], gp[8];
  #pragma unroll
  for (int k=0;k<32;k++){ hp[k]=hs[g*32+k]; rp[k]=rvec[g*32+k]; }
  #pragma unroll
  for (int k=0;k<8;k++) gp[k]=ga[g*8+k];
  float o = b2[0];
  for (int j=0;j<32;j++){
    float acc = sb1[j];
    #pragma unroll
    for (int k=0;k<32;k++) acc += hp[k]*sw1[k*32+j];
    #pragma unroll
    for (int k=0;k<32;k++) acc += rp[k]*sw1[(32+k)*32+j];
    #pragma unroll
    for (int k=0;k<8;k++)  acc += gp[k]*sw1[(64+k)*32+j];
    o += fmaxf(acc,0.f)*sw2[j];
  }
  out[g] = o;
}

// ---------------- launch ----------------
extern "C" void kernel_launch(void* const* d_in, const int* in_sizes, int n_in,
                              void* d_out, int out_size, void* d_ws, size_t ws_size,
                              hipStream_t stream){
  (void)in_sizes; (void)n_in; (void)out_size;
  const float* x         = (const float*)d_in[0];
  const float* edge_attr = (const float*)d_in[1];
  const float* graph_attr= (const float*)d_in[2];
  const int*   eidx      = (const int*)d_in[3];
  const int*   batch     = (const int*)d_in[4];
  const float* lin0_w    = (const float*)d_in[5];
  const float* lin0_b    = (const float*)d_in[6];
  const float* nn1_w     = (const float*)d_in[7];
  const float* nn1_b     = (const float*)d_in[8];
  const float* nn2_w     = (const float*)d_in[9];
  const float* nn2_b     = (const float*)d_in[10];
  const float* root_w    = (const float*)d_in[11];
  const float* conv_b    = (const float*)d_in[12];
  const float* gru_wih   = (const float*)d_in[13];
  const float* gru_whh   = (const float*)d_in[14];
  const float* gru_bih   = (const float*)d_in[15];
  const float* gru_bhh   = (const float*)d_in[16];
  const float* lstm_wih  = (const float*)d_in[17];
  const float* lstm_whh  = (const float*)d_in[18];
  const float* lstm_bih  = (const float*)d_in[19];
  const float* lstm_bhh  = (const float*)d_in[20];
  const float* lin1_w    = (const float*)d_in[21];
  const float* lin1_b    = (const float*)d_in[22];
  const float* lin2_w    = (const float*)d_in[23];
  const float* lin2_b    = (const float*)d_in[24];
  const int* src = eidx;
  const int* dst = eidx + NED;

  char* pool = (ws_size >= kNeed) ? (char*)d_ws : (char*)g_fb;
  if (!pool) pool = (char*)d_ws;   // last resort
  size_t off = 0;
  auto alloc = [&](size_t bytes)->char* {
    char* p = pool + off; off += (bytes + 511) & ~(size_t)511; return p;
  };
  unsigned short* ew  = (unsigned short*)alloc((size_t)NED*1024*2);  // 409.6 MB, bf16 [e][o*32+d]
  unsigned short* H   = (unsigned short*)alloc((size_t)NED*128*2);   // 51.2 MB, bf16
  float* cur  = (float*)alloc((size_t)NND*32*4);
  float* agg  = (float*)alloc((size_t)NND*32*4);
  float* deg  = (float*)alloc((size_t)NND*4);
  float* ev   = (float*)alloc((size_t)NND*4);
  unsigned short* Btb = (unsigned short*)alloc(1024*128*2);          // bf16 [p][k]
  float* b2t  = (float*)alloc(1024*4);
  float* hsb  = (float*)alloc(NG*32*4);
  float* csb  = (float*)alloc(NG*32*4);
  float* rvb  = (float*)alloc(NG*32*4);
  int*   counts = (int*)alloc(512);
  int*   startsb= (int*)alloc(512);

  hipMemsetAsync(deg, 0, (size_t)NND*4, stream);
  hipMemsetAsync(agg, 0, (size_t)NND*32*4, stream);
  hipMemsetAsync(hsb, 0, NG*32*4, stream);
  hipMemsetAsync(csb, 0, NG*32*4, stream);
  hipMemsetAsync(rvb, 0, NG*32*4, stream);

  k_prep<<<512, 256, 0, stream>>>(nn2_w, nn2_b, Btb, b2t);
  k_lin0<<<(NND+31)/32, 256, 0, stream>>>(x, lin0_w, lin0_b, cur);
  k_starts<<<1, 128, 0, stream>>>(batch, startsb, counts);
  k_deg<<<(NED+255)/256, 256, 0, stream>>>(dst, deg);
  k_hidden<<<NED*32/256, 256, 0, stream>>>(edge_attr, nn1_w, nn1_b, H);
  k_gemm2m<<<NED/64, 256, 0, stream>>>(H, Btb, b2t, ew);

  for (int it=0; it<3; ++it){
    k_msg<<<NED*32/256, 256, 0, stream>>>(cur, ew, src, dst, agg);
    k_gru<<<NND/32, 256, 0, stream>>>(cur, agg, deg, root_w, conv_b,
                                      gru_wih, gru_whh, gru_bih, gru_bhh);
  }
  for (int st=0; st<3; ++st){
    k_lstm<<<1, 128, 0, stream>>>(hsb, csb, rvb, lstm_wih, lstm_whh, lstm_bih, lstm_bhh);
    k_attn<<<NG, 256, 0, stream>>>(cur, hsb, startsb, counts, ev, rvb);
  }
  k_final<<<1, 128, 0, stream>>>(hsb, rvb, graph_attr, lin1_w, lin1_b, lin2_w, lin2_b, (float*)d_out);
}

// Round 5
// 926.914 us; speedup vs baseline: 4.5689x; 1.3576x over previous
//
#include <hip/hip_runtime.h>
#include <stdint.h>
#include <stddef.h>

// ---------------- problem constants ----------------
#define NND 100000   // nodes
#define NED 200000   // edges
#define NG  128      // graphs
// D=32, D_LIN=128, F_EDGE=16, F_GRAPH=8, MP_TIMES=3, STEPS=3

typedef unsigned short us8 __attribute__((ext_vector_type(8)));
typedef unsigned short us4v __attribute__((ext_vector_type(4)));
typedef short bf16x8 __attribute__((ext_vector_type(8)));
typedef float f32x4 __attribute__((ext_vector_type(4)));

__device__ __forceinline__ float bf2f(unsigned short u){
  union{unsigned u; float f;} v; v.u = ((unsigned)u)<<16; return v.f;
}
__device__ __forceinline__ unsigned short f2bf(float f){
  union{float f; unsigned u;} v; v.f = f;
  unsigned r = v.u + 0x7FFFu + ((v.u>>16)&1u);
  return (unsigned short)(r>>16);
}
__device__ __forceinline__ float sigm(float x){ return 1.f/(1.f+__expf(-x)); }
__device__ __forceinline__ float tanh_(float x){ return 2.f/(1.f+__expf(-2.f*x)) - 1.f; }

// ---------------- fallback workspace (ws_size may be < 540MB) ----------------
static const size_t kNeed = 540000000ull;
static void* g_fb = nullptr;
namespace {
struct FB { FB(){ if (hipMalloc(&g_fb, kNeed) != hipSuccess) g_fb = nullptr; } };
static FB g_fb_init;
}

// ---------------- kernels ----------------

// blocks 0-511: Btb[p][k] = bf16(nn2[k][d*32+o]) (p=o*32+d), b2t
// block 512   : starts/counts via binary search over sorted batch
// blocks 513+ : zero agg and deg
__global__ __launch_bounds__(256) void k_misc(const float* __restrict__ nn2, const float* __restrict__ b2,
                                              unsigned short* __restrict__ Btb, float* __restrict__ b2t,
                                              const int* __restrict__ batch,
                                              int* __restrict__ starts, int* __restrict__ counts,
                                              float* __restrict__ deg, float* __restrict__ agg){
  int b = blockIdx.x;
  if (b < 512){
    int tid = b*256 + threadIdx.x;     // 128*1024 total
    int k = tid >> 10, p = tid & 1023;
    int q = ((p & 31) << 5) + (p >> 5);
    Btb[p*128 + k] = f2bf(nn2[(k << 10) + q]);
    if (k == 0) b2t[p] = b2[q];
  } else if (b == 512){
    __shared__ int s[129];
    int g = threadIdx.x;
    if (g < 128){
      int lo = 0, hi = NND;
      while (lo < hi){ int mid = (lo + hi) >> 1; if (batch[mid] < g) lo = mid + 1; else hi = mid; }
      s[g] = lo;
      if (g == 0) s[128] = NND;
    }
    __syncthreads();
    if (g < 128){ starts[g] = s[g]; counts[g] = s[g+1] - s[g]; }
  } else {
    int idx = (b - 513)*256 + threadIdx.x;   // grid 1024 -> 511 zero-blocks
    const int stride = 511*256;
    float4 z; z.x=0.f; z.y=0.f; z.z=0.f; z.w=0.f;
    for (int i = idx; i < (NND*32)/4; i += stride) ((float4*)agg)[i] = z;
    for (int i = idx; i < NND; i += stride) deg[i] = 0.f;
  }
}

// cur = relu(x @ lin0_w + lin0_b)  -- 32 lanes per node, lane j owns output j
__global__ __launch_bounds__(256) void k_lin0(const float* __restrict__ x, const float* __restrict__ w,
                                              const float* __restrict__ b, float* __restrict__ cur){
  __shared__ float sw[1024]; __shared__ float sb[32];
  __shared__ float sx[8][32];
  for (int i = threadIdx.x; i < 1024; i += 256) sw[i] = w[i];
  if (threadIdx.x < 32) sb[threadIdx.x] = b[threadIdx.x];
  __syncthreads();
  int ln = threadIdx.x >> 5, j = threadIdx.x & 31;
  for (int it = 0; it < 4; ++it){
    int n = (blockIdx.x*4 + it)*8 + ln;
    if (n >= NND) return;
    float xj = x[(size_t)n*32 + j];
    sx[ln][j] = xj;                       // wave-synchronous within the 32-lane group
    float acc = sb[j];
    #pragma unroll
    for (int d=0; d<32; d++) acc += sx[ln][d]*sw[d*32+j];
    cur[(size_t)n*32 + j] = fmaxf(acc, 0.f);
  }
}

// H = relu(edge_attr @ nn1 + b1)   [E,128] bf16; 32 threads/edge, 4 outputs each
__global__ __launch_bounds__(256) void k_hidden(const float* __restrict__ ea, const float* __restrict__ w1,
                                                const float* __restrict__ b1, unsigned short* __restrict__ H){
  __shared__ float sw[2048]; __shared__ float sb[128];
  for (int i=threadIdx.x;i<2048;i+=256) sw[i]=w1[i];
  if (threadIdx.x<128) sb[threadIdx.x]=b1[threadIdx.x];
  __syncthreads();
  int gid = blockIdx.x*256 + threadIdx.x;     // E*32 total, exact
  int e = gid >> 5, q = gid & 31;
  float a[16];
  const float4* ap = (const float4*)(ea + (size_t)e*16);
  #pragma unroll
  for (int i=0;i<4;i++){ float4 v=ap[i]; a[4*i]=v.x; a[4*i+1]=v.y; a[4*i+2]=v.z; a[4*i+3]=v.w; }
  float c0=sb[q*4], c1=sb[q*4+1], c2=sb[q*4+2], c3=sb[q*4+3];
  #pragma unroll
  for (int k=0;k<16;k++){
    float av=a[k]; const float* wr = &sw[k*128 + q*4];
    c0 += av*wr[0]; c1 += av*wr[1]; c2 += av*wr[2]; c3 += av*wr[3];
  }
  us4v o;
  o[0]=f2bf(fmaxf(c0,0.f)); o[1]=f2bf(fmaxf(c1,0.f));
  o[2]=f2bf(fmaxf(c2,0.f)); o[3]=f2bf(fmaxf(c3,0.f));
  *(us4v*)(H + (size_t)e*128 + q*4) = o;
}

// MFMA GEMM: ew[64e x 1024] = Hb[64e x 128k] @ Btb[1024p x 128k]^T + b2t, bf16 out.
// One block = 64 edges, loops 8 column-groups of 128. 4 waves: 2x2 of 32r x 64c.
__global__ __launch_bounds__(256) void k_gemm2m(const unsigned short* __restrict__ Hb,
                                                const unsigned short* __restrict__ Btb,
                                                const float* __restrict__ b2t,
                                                unsigned short* __restrict__ ew){
  __shared__ char smem[49152];           // sA 16KB | sB 32KB ; sC aliases sA
  char* sA = smem;
  char* sB = smem + 16384;
  int tid = threadIdx.x;
  int e0 = blockIdx.x * 64;
  int l = tid & 63, wv = tid >> 6;
  int wr = wv >> 1, wc = wv & 1;

  // stage A: 64 rows x 256B (XOR-swizzled), 4 passes of 16 rows
  {
    int r = tid >> 4, c16 = (tid & 15) * 16;
    #pragma unroll
    for (int pass = 0; pass < 4; ++pass){
      int row = pass*16 + r;
      bf16x8 v = *(const bf16x8*)(Hb + (size_t)(e0+row)*128 + (tid&15)*8);
      *(bf16x8*)(sA + row*256 + (c16 ^ ((row&7)<<4))) = v;
    }
  }
  __syncthreads();
  // A fragments to regs (sA free for reuse afterwards): [mi][ks]
  bf16x8 afr[2][4];
  #pragma unroll
  for (int mi=0; mi<2; ++mi){
    int row = wr*32 + mi*16 + (l & 15);
    #pragma unroll
    for (int ks=0; ks<4; ++ks){
      int kb = ks*64 + (l>>4)*16;
      afr[mi][ks] = *(bf16x8*)(sA + row*256 + (kb ^ ((row&7)<<4)));
    }
  }

  for (int cg = 0; cg < 8; ++cg){
    __syncthreads();                     // prev sB/sC consumers done
    // stage B strip: 128 p-rows x 256B (XOR-swizzled), 8 passes of 16 rows
    {
      int rr = tid >> 4, cc = tid & 15;
      #pragma unroll
      for (int pass = 0; pass < 8; ++pass){
        int p = pass*16 + rr;
        bf16x8 v = *(const bf16x8*)(Btb + (size_t)(cg*128 + p)*128 + cc*8);
        *(bf16x8*)(sB + p*256 + ((cc*16) ^ ((p&7)<<4))) = v;
      }
    }
    __syncthreads();
    float bz[4];
    #pragma unroll
    for (int ni=0; ni<4; ++ni) bz[ni] = b2t[cg*128 + wc*64 + ni*16 + (l&15)];
    f32x4 acc[2][4];
    #pragma unroll
    for (int mi=0; mi<2; ++mi)
      #pragma unroll
      for (int ni=0; ni<4; ++ni){
        f32x4 a; a[0]=bz[ni]; a[1]=bz[ni]; a[2]=bz[ni]; a[3]=bz[ni];
        acc[mi][ni] = a;
      }
    #pragma unroll
    for (int ks=0; ks<4; ++ks){
      bf16x8 bfr[4];
      #pragma unroll
      for (int ni=0; ni<4; ++ni){
        int p = wc*64 + ni*16 + (l&15);
        int kb = ks*64 + (l>>4)*16;
        bfr[ni] = *(bf16x8*)(sB + p*256 + (kb ^ ((p&7)<<4)));
      }
      #pragma unroll
      for (int mi=0; mi<2; ++mi)
        #pragma unroll
        for (int ni=0; ni<4; ++ni)
          acc[mi][ni] = __builtin_amdgcn_mfma_f32_16x16x32_bf16(afr[mi][ks], bfr[ni], acc[mi][ni], 0, 0, 0);
    }
    // C bounce: write bf16 into swizzled sC (=sA), then linear read + permuted coalesced store
    char* sC = sA;
    #pragma unroll
    for (int mi=0; mi<2; ++mi)
      #pragma unroll
      for (int ni=0; ni<4; ++ni){
        int colb = (wc*64 + ni*16 + (l&15)) * 2;
        #pragma unroll
        for (int q=0; q<4; ++q){
          int row = wr*32 + mi*16 + (l>>4)*4 + q;
          *(unsigned short*)(sC + row*256 + (colb ^ ((row&7)<<4))) = f2bf(acc[mi][ni][q]);
        }
      }
    __syncthreads();
    #pragma unroll
    for (int i=0; i<4; ++i){
      int L = i*4096 + tid*16;
      int row = L >> 8, bin = L & 255;
      int ub = bin ^ ((row&7)<<4);       // unswizzled byte-in-row
      bf16x8 v = *(bf16x8*)(sC + L);
      *(bf16x8*)(ew + (size_t)(e0+row)*1024 + cg*128 + (ub>>1)) = v;
    }
  }
}

__global__ __launch_bounds__(256) void k_deg(const int* __restrict__ dst, float* __restrict__ deg){
  int e = blockIdx.x*256 + threadIdx.x;
  if (e < NED) atomicAdd(&deg[dst[e]], 1.f);
}

// msg[e,o] = sum_d cur[src[e],d]*ew[e][o*32+d];  atomicAdd into agg[dst,o].  32 lanes/edge.
__global__ __launch_bounds__(256) void k_msg(const float* __restrict__ cur, const unsigned short* __restrict__ ew,
                                             const int* __restrict__ src, const int* __restrict__ dst,
                                             float* __restrict__ agg){
  __shared__ float s_lds[8][32];
  int gid = blockIdx.x*256 + threadIdx.x;     // E*32 exact
  int e = gid >> 5, o = gid & 31, le = threadIdx.x >> 5;
  int s = src[e], t = dst[e];
  s_lds[le][o] = cur[(size_t)s*32 + o];
  __syncthreads();
  float acc = 0.f;
  const unsigned short* er = ew + (size_t)e*1024 + o*32;
  const float* sr = s_lds[le];
  #pragma unroll
  for (int d0=0; d0<32; d0+=8){
    us8 u = *(const us8*)(er + d0);
    #pragma unroll
    for (int j=0;j<8;j++) acc += bf2f(u[j]) * sr[d0+j];
  }
  atomicAdd(&agg[(size_t)t*32 + o], acc);
}

// m = relu(cur@root + agg/deg + cb); GRU(h=cur, in=m) -> cur. Zeroes agg after read.
// 32 lanes per node (lane j owns channel j); 8 nodes per 256-thr block-slice, 4 slices.
__global__ __launch_bounds__(256) void k_gru(float* __restrict__ cur, float* __restrict__ agg,
                                             const float* __restrict__ deg,
                                             const float* __restrict__ root_w, const float* __restrict__ conv_b,
                                             const float* __restrict__ wih, const float* __restrict__ whh,
                                             const float* __restrict__ bih, const float* __restrict__ bhh){
  __shared__ float s_root[1024], s_wih[3072], s_whh[3072], s_cb[32], s_bih[96], s_bhh[96];
  __shared__ float s_c[8][32], s_m[8][32];
  for (int i=threadIdx.x;i<1024;i+=256) s_root[i]=root_w[i];
  for (int i=threadIdx.x;i<3072;i+=256){ s_wih[i]=wih[i]; s_whh[i]=whh[i]; }
  if (threadIdx.x<32) s_cb[threadIdx.x]=conv_b[threadIdx.x];
  if (threadIdx.x<96){ s_bih[threadIdx.x]=bih[threadIdx.x]; s_bhh[threadIdx.x]=bhh[threadIdx.x]; }
  __syncthreads();
  int ln = threadIdx.x >> 5, j = threadIdx.x & 31;
  for (int it = 0; it < 4; ++it){
    int n = (blockIdx.x*4 + it)*8 + ln;
    float c_j = cur[(size_t)n*32 + j];
    float a_j = agg[(size_t)n*32 + j];
    agg[(size_t)n*32 + j] = 0.f;       // re-zero for next k_msg pass
    s_c[ln][j] = c_j;
    float idg = 1.f / fmaxf(deg[n], 1.f);
    float acc = s_cb[j] + a_j*idg;
    #pragma unroll
    for (int d=0; d<32; d++) acc += s_c[ln][d]*s_root[d*32+j];
    float m_j = fmaxf(acc, 0.f);
    s_m[ln][j] = m_j;
    float gr = s_bih[j], gz = s_bih[32+j], gn = s_bih[64+j];
    float hr = s_bhh[j], hz = s_bhh[32+j], hh = s_bhh[64+j];
    #pragma unroll
    for (int k=0;k<32;k++){
      float mk = s_m[ln][k], ck = s_c[ln][k];
      gr += mk*s_wih[k*96+j];
      gz += mk*s_wih[k*96+32+j];
      gn += mk*s_wih[k*96+64+j];
      hr += ck*s_whh[k*96+j];
      hz += ck*s_whh[k*96+32+j];
      hh += ck*s_whh[k*96+64+j];
    }
    float r = sigm(gr+hr);
    float z = sigm(gz+hz);
    float nnv = tanh_(gn + r*hh);
    cur[(size_t)n*32 + j] = (1.f-z)*nnv + z*c_j;
  }
}

// Fused Set2Set (3 steps LSTM + segment-softmax attention) + final MLP.
// One block per graph; hs/cs/rv live in LDS; weights read from L2 directly.
__global__ __launch_bounds__(256) void k_s2s(const float* __restrict__ cur,
                                             const int* __restrict__ starts, const int* __restrict__ counts,
                                             const float* __restrict__ ga,
                                             const float* __restrict__ lwih, const float* __restrict__ lwhh,
                                             const float* __restrict__ lbih, const float* __restrict__ lbhh,
                                             const float* __restrict__ w1, const float* __restrict__ b1,
                                             const float* __restrict__ w2, const float* __restrict__ b2,
                                             float* __restrict__ ev, float* __restrict__ out){
  int g = blockIdx.x;
  int s0 = starts[g], cnt = counts[g];
  int tid = threadIdx.x;
  __shared__ float hs[32], cs[32], rv[32], sg[128];
  __shared__ float red[256];
  if (tid < 32){ hs[tid]=0.f; cs[tid]=0.f; rv[tid]=0.f; }
  __syncthreads();
  for (int step=0; step<3; ++step){
    // LSTM: thread j<128 computes gate j (q_star = [hs, rv])
    if (tid < 128){
      int j = tid;
      float acc = lbih[j] + lbhh[j];
      #pragma unroll 8
      for (int k=0;k<32;k++){
        acc += hs[k]*(lwih[k*128+j] + lwhh[k*128+j]);
        acc += rv[k]*lwih[(32+k)*128+j];
      }
      sg[j] = acc;
    }
    __syncthreads();
    if (tid < 32){
      int j = tid;
      float cn = sigm(sg[32+j])*cs[j] + sigm(sg[j])*tanh_(sg[64+j]);
      cs[j] = cn;
      hs[j] = sigm(sg[96+j])*tanh_(cn);
    }
    __syncthreads();
    // attention pass 1: e = cur . hs, track max
    float lmax = -3.4e38f;
    for (int i = tid; i < cnt; i += 256){
      const float4* cp = (const float4*)(cur + (size_t)(s0+i)*32);
      float acc = 0.f;
      #pragma unroll
      for (int q=0;q<8;q++){ float4 v=cp[q]; acc += v.x*hs[q*4]+v.y*hs[q*4+1]+v.z*hs[q*4+2]+v.w*hs[q*4+3]; }
      ev[s0+i] = acc;
      lmax = fmaxf(lmax, acc);
    }
    red[tid] = lmax; __syncthreads();
    #pragma unroll
    for (int st=128; st>0; st>>=1){ if (tid<st) red[tid]=fmaxf(red[tid],red[tid+st]); __syncthreads(); }
    float mx = red[0]; __syncthreads();
    // pass 2: w = exp(e-mx); accumulate sumw and vec = sum w*cur
    float vec[32];
    #pragma unroll
    for (int k=0;k<32;k++) vec[k]=0.f;
    float lsum = 0.f;
    for (int i = tid; i < cnt; i += 256){
      float w = __expf(ev[s0+i]-mx);
      lsum += w;
      const float4* cp = (const float4*)(cur + (size_t)(s0+i)*32);
      #pragma unroll
      for (int q=0;q<8;q++){ float4 v=cp[q]; vec[q*4]+=w*v.x; vec[q*4+1]+=w*v.y; vec[q*4+2]+=w*v.z; vec[q*4+3]+=w*v.w; }
    }
    red[tid] = lsum; __syncthreads();
    #pragma unroll
    for (int st=128; st>0; st>>=1){ if (tid<st) red[tid]+=red[tid+st]; __syncthreads(); }
    float inv = 1.f/red[0];
    if (tid < 32) rv[tid] = 0.f;
    __syncthreads();
    #pragma unroll
    for (int k=0;k<32;k++){
      float v = vec[k];
      #pragma unroll
      for (int o=32;o>0;o>>=1) v += __shfl_down(v, o, 64);
      if ((tid&63)==0) atomicAdd(&rv[k], v);
    }
    __syncthreads();
    if (tid < 32) rv[tid] *= inv;
    __syncthreads();
  }
  // final: unit j of relu layer, then wave-reduce to out[g]
  if (tid < 32){
    int j = tid;
    float acc = b1[j];
    #pragma unroll 8
    for (int k=0;k<32;k++) acc += hs[k]*w1[k*32+j];
    #pragma unroll 8
    for (int k=0;k<32;k++) acc += rv[k]*w1[(32+k)*32+j];
    #pragma unroll
    for (int k=0;k<8;k++)  acc += ga[g*8+k]*w1[(64+k)*32+j];
    float r = fmaxf(acc, 0.f)*w2[j];
    #pragma unroll
    for (int o=16;o>0;o>>=1) r += __shfl_down(r, o, 64);
    if (j == 0) out[g] = r + b2[0];
  }
}

// ---------------- launch ----------------
extern "C" void kernel_launch(void* const* d_in, const int* in_sizes, int n_in,
                              void* d_out, int out_size, void* d_ws, size_t ws_size,
                              hipStream_t stream){
  (void)in_sizes; (void)n_in; (void)out_size;
  const float* x         = (const float*)d_in[0];
  const float* edge_attr = (const float*)d_in[1];
  const float* graph_attr= (const float*)d_in[2];
  const int*   eidx      = (const int*)d_in[3];
  const int*   batch     = (const int*)d_in[4];
  const float* lin0_w    = (const float*)d_in[5];
  const float* lin0_b    = (const float*)d_in[6];
  const float* nn1_w     = (const float*)d_in[7];
  const float* nn1_b     = (const float*)d_in[8];
  const float* nn2_w     = (const float*)d_in[9];
  const float* nn2_b     = (const float*)d_in[10];
  const float* root_w    = (const float*)d_in[11];
  const float* conv_b    = (const float*)d_in[12];
  const float* gru_wih   = (const float*)d_in[13];
  const float* gru_whh   = (const float*)d_in[14];
  const float* gru_bih   = (const float*)d_in[15];
  const float* gru_bhh   = (const float*)d_in[16];
  const float* lstm_wih  = (const float*)d_in[17];
  const float* lstm_whh  = (const float*)d_in[18];
  const float* lstm_bih  = (const float*)d_in[19];
  const float* lstm_bhh  = (const float*)d_in[20];
  const float* lin1_w    = (const float*)d_in[21];
  const float* lin1_b    = (const float*)d_in[22];
  const float* lin2_w    = (const float*)d_in[23];
  const float* lin2_b    = (const float*)d_in[24];
  const int* src = eidx;
  const int* dst = eidx + NED;

  char* pool = (ws_size >= kNeed) ? (char*)d_ws : (char*)g_fb;
  if (!pool) pool = (char*)d_ws;   // last resort
  size_t off = 0;
  auto alloc = [&](size_t bytes)->char* {
    char* p = pool + off; off += (bytes + 511) & ~(size_t)511; return p;
  };
  unsigned short* ew  = (unsigned short*)alloc((size_t)NED*1024*2);  // 409.6 MB, bf16 [e][o*32+d]
  unsigned short* H   = (unsigned short*)alloc((size_t)NED*128*2);   // 51.2 MB, bf16
  float* cur  = (float*)alloc((size_t)NND*32*4);
  float* agg  = (float*)alloc((size_t)NND*32*4);
  float* deg  = (float*)alloc((size_t)NND*4);
  float* ev   = (float*)alloc((size_t)NND*4);
  unsigned short* Btb = (unsigned short*)alloc(1024*128*2);          // bf16 [p][k]
  float* b2t  = (float*)alloc(1024*4);
  int*   counts = (int*)alloc(512);
  int*   startsb= (int*)alloc(512);

  k_misc<<<1024, 256, 0, stream>>>(nn2_w, nn2_b, Btb, b2t, batch, startsb, counts, deg, agg);
  k_lin0<<<(NND+31)/32, 256, 0, stream>>>(x, lin0_w, lin0_b, cur);
  k_hidden<<<NED*32/256, 256, 0, stream>>>(edge_attr, nn1_w, nn1_b, H);
  k_gemm2m<<<NED/64, 256, 0, stream>>>(H, Btb, b2t, ew);
  k_deg<<<(NED+255)/256, 256, 0, stream>>>(dst, deg);

  for (int it=0; it<3; ++it){
    k_msg<<<NED*32/256, 256, 0, stream>>>(cur, ew, src, dst, agg);
    k_gru<<<NND/32, 256, 0, stream>>>(cur, agg, deg, root_w, conv_b,
                                      gru_wih, gru_whh, gru_bih, gru_bhh);
  }
  k_s2s<<<NG, 256, 0, stream>>>(cur, startsb, counts, graph_attr,
                                lstm_wih, lstm_whh, lstm_bih, lstm_bhh,
                                lin1_w, lin1_b, lin2_w, lin2_b, ev, (float*)d_out);
}